// Round 4
// baseline (3163.609 us; speedup 1.0000x reference)
//
#include <hip/hip_runtime.h>

#define DIN 512
#define DH  64
#define BKT_SHIFT 7                 // 128 nodes per bucket
#define BKT_NODES 128
#define MAXBKT 1024                 // supports up to 131072 nodes
#define TILE 8192                   // edges per binning workgroup
#define SRC_BITS 17                 // n_nodes < 131072

// ---------------- small precompute: Wc = W2@Wlin, bias_out = b2@Wlin + blin ----
__global__ __launch_bounds__(256) void k_wc(const float* __restrict__ W2,
                                            const float* __restrict__ b2,
                                            const float* __restrict__ Wlin,
                                            const float* __restrict__ blin,
                                            float* __restrict__ Wc,
                                            float* __restrict__ bias_out) {
  int tid = threadIdx.x;
  for (int idx = tid; idx < 64 * 64; idx += 256) {
    int i = idx >> 6, j = idx & 63;
    float s = 0.f;
    #pragma unroll 8
    for (int k = 0; k < 64; ++k) s = fmaf(W2[i * 64 + k], Wlin[k * 64 + j], s);
    Wc[idx] = s;
  }
  if (tid < 64) {
    float s = blin[tid];
    #pragma unroll 8
    for (int k = 0; k < 64; ++k) s = fmaf(b2[k], Wlin[k * 64 + tid], s);
    bias_out[tid] = s;
  }
}

// ---------------- pass 0: per-bucket edge counts (tile-aggregated) ------------
__global__ __launch_bounds__(256) void k_cnt(const int* __restrict__ dst, int n_edges,
                                             int* __restrict__ gtot, int nbkt) {
  __shared__ int cnt[MAXBKT];
  for (int b = threadIdx.x; b < nbkt; b += 256) cnt[b] = 0;
  __syncthreads();
  int e0 = blockIdx.x * TILE;
  int e1 = min(e0 + TILE, n_edges);
  for (int e = e0 + threadIdx.x; e < e1; e += 256)
    atomicAdd(&cnt[dst[e] >> BKT_SHIFT], 1);
  __syncthreads();
  for (int b = threadIdx.x; b < nbkt; b += 256) {
    int c = cnt[b];
    if (c) atomicAdd(&gtot[b], c);
  }
}

// ---------------- scan bucket counts -> boff[0..nbkt], copy to gcur -----------
__global__ __launch_bounds__(256) void k_bscan(const int* __restrict__ gtot, int nbkt,
                                               int* __restrict__ boff,
                                               int* __restrict__ gcur) {
  __shared__ int sh[256];
  int t = threadIdx.x;
  int base = t * 4;
  int v[4];
  int s = 0;
  #pragma unroll
  for (int k = 0; k < 4; ++k) {
    int i = base + k;
    v[k] = (i < nbkt) ? gtot[i] : 0;
    s += v[k];
  }
  sh[t] = s;
  __syncthreads();
  for (int off = 1; off < 256; off <<= 1) {
    int x = sh[t];
    int y = (t >= off) ? sh[t - off] : 0;
    __syncthreads();
    sh[t] = x + y;
    __syncthreads();
  }
  int excl = sh[t] - s;
  #pragma unroll
  for (int k = 0; k < 4; ++k) {
    int i = base + k;
    if (i < nbkt) { boff[i] = excl; gcur[i] = excl; }
    excl += v[k];
  }
  if (t == 255) boff[nbkt] = sh[255];
}

// ---------------- pass 1: bin edges into buckets, 4B packed entries -----------
__global__ __launch_bounds__(256) void k_bin(const int* __restrict__ src,
                                             const int* __restrict__ dst, int n_edges,
                                             int* __restrict__ gcur,
                                             unsigned int* __restrict__ tmp, int nbkt) {
  __shared__ int cnt[MAXBKT];
  __shared__ int base[MAXBKT];
  int t = threadIdx.x;
  for (int b = t; b < nbkt; b += 256) cnt[b] = 0;
  __syncthreads();
  int e0 = blockIdx.x * TILE;
  int e1 = min(e0 + TILE, n_edges);
  for (int e = e0 + t; e < e1; e += 256)
    atomicAdd(&cnt[dst[e] >> BKT_SHIFT], 1);
  __syncthreads();
  for (int b = t; b < nbkt; b += 256) {
    int c = cnt[b];
    base[b] = c ? atomicAdd(&gcur[b], c) : 0;
    cnt[b] = 0;
  }
  __syncthreads();
  for (int e = e0 + t; e < e1; e += 256) {
    int d = dst[e];
    int bkt = d >> BKT_SHIFT;
    int off = atomicAdd(&cnt[bkt], 1);
    tmp[base[bkt] + off] =
        (unsigned int)src[e] | ((unsigned int)(d & (BKT_NODES - 1)) << SRC_BITS);
  }
}

// ---------------- degrees -> dinv, from binned entries ------------------------
__global__ __launch_bounds__(256) void k_ddinv(const unsigned int* __restrict__ tmp,
                                               const int* __restrict__ boff,
                                               float* __restrict__ dinv, int n_nodes) {
  __shared__ int cnt[BKT_NODES];
  int bkt = blockIdx.x;
  if (threadIdx.x < BKT_NODES) cnt[threadIdx.x] = 0;
  __syncthreads();
  int beg = boff[bkt], end = boff[bkt + 1];
  for (int j = beg + threadIdx.x; j < end; j += 256)
    atomicAdd(&cnt[tmp[j] >> SRC_BITS], 1);
  __syncthreads();
  if (threadIdx.x < BKT_NODES) {
    int node = (bkt << BKT_SHIFT) + threadIdx.x;
    if (node < n_nodes) dinv[node] = rsqrtf((float)(cnt[threadIdx.x] + 1));
  }
}

// ---------------- fp32 tiled GEMM: C[M,64] = A[M,K] @ B[K,64] -----------------
__global__ __launch_bounds__(256) void k_gemm(const float* __restrict__ A,
                                              const float* __restrict__ B,
                                              float* __restrict__ C,
                                              int M, int K) {
  __shared__ float As[16][68];
  __shared__ float Bs[16][64];
  const int tid = threadIdx.x;
  const int block_m = blockIdx.x * 64;
  const int tm = (tid >> 4) * 4;
  const int tn = (tid & 15) * 4;
  const int lm = tid >> 2;
  const int lk = (tid & 3) * 4;
  const int bk = tid >> 4;
  const int bn = (tid & 15) * 4;

  float acc[4][4] = {{0.f}};

  for (int k0 = 0; k0 < K; k0 += 16) {
    float4 a = make_float4(0.f, 0.f, 0.f, 0.f);
    int an = block_m + lm;
    if (an < M) a = *(const float4*)&A[(size_t)an * K + k0 + lk];
    As[lk + 0][lm] = a.x;
    As[lk + 1][lm] = a.y;
    As[lk + 2][lm] = a.z;
    As[lk + 3][lm] = a.w;
    *(float4*)&Bs[bk][bn] = *(const float4*)&B[(size_t)(k0 + bk) * 64 + bn];
    __syncthreads();
    #pragma unroll
    for (int k = 0; k < 16; ++k) {
      float4 av = *(const float4*)&As[k][tm];
      float4 bv = *(const float4*)&Bs[k][tn];
      acc[0][0] = fmaf(av.x, bv.x, acc[0][0]);
      acc[0][1] = fmaf(av.x, bv.y, acc[0][1]);
      acc[0][2] = fmaf(av.x, bv.z, acc[0][2]);
      acc[0][3] = fmaf(av.x, bv.w, acc[0][3]);
      acc[1][0] = fmaf(av.y, bv.x, acc[1][0]);
      acc[1][1] = fmaf(av.y, bv.y, acc[1][1]);
      acc[1][2] = fmaf(av.y, bv.z, acc[1][2]);
      acc[1][3] = fmaf(av.y, bv.w, acc[1][3]);
      acc[2][0] = fmaf(av.z, bv.x, acc[2][0]);
      acc[2][1] = fmaf(av.z, bv.y, acc[2][1]);
      acc[2][2] = fmaf(av.z, bv.z, acc[2][2]);
      acc[2][3] = fmaf(av.z, bv.w, acc[2][3]);
      acc[3][0] = fmaf(av.w, bv.x, acc[3][0]);
      acc[3][1] = fmaf(av.w, bv.y, acc[3][1]);
      acc[3][2] = fmaf(av.w, bv.z, acc[3][2]);
      acc[3][3] = fmaf(av.w, bv.w, acc[3][3]);
    }
    __syncthreads();
  }
  #pragma unroll
  for (int i = 0; i < 4; ++i) {
    int row = block_m + tm + i;
    if (row < M) {
      float4 r = make_float4(acc[i][0], acc[i][1], acc[i][2], acc[i][3]);
      *(float4*)&C[(size_t)row * 64 + tn] = r;
    }
  }
}

// ---- bucket gather with LDS accumulators + fused self-loop/bias/ReLU ---------
// one workgroup per 128-node bucket; lane = feature channel;
// out[n,l] = act( dinv[n] * sum_e dinv[s_e]*feat[s_e,l] + dinv[n]^2*feat[n,l] + bias[l] )
__global__ __launch_bounds__(256) void k_gather(const float* __restrict__ feat,
                                                const unsigned int* __restrict__ tmp,
                                                const int* __restrict__ boff,
                                                const float* __restrict__ dinv,
                                                const float* __restrict__ bias,
                                                float* __restrict__ out,
                                                int n_nodes, int relu) {
  __shared__ float sacc[BKT_NODES * 64];  // 32 KB
  const int t = threadIdx.x;
  for (int i = t; i < BKT_NODES * 64 / 4; i += 256)
    ((float4*)sacc)[i] = make_float4(0.f, 0.f, 0.f, 0.f);
  __syncthreads();

  const int bkt = blockIdx.x;
  const int beg = boff[bkt], end = boff[bkt + 1];
  const int w = t >> 6, lane = t & 63;
  const int len = end - beg;
  const int per = (len + 3) >> 2;
  const int jb = beg + w * per;
  const int je = min(jb + per, end);

  int j = jb;
  for (; j + 4 <= je; j += 4) {
    unsigned int e0 = tmp[j], e1 = tmp[j + 1], e2 = tmp[j + 2], e3 = tmp[j + 3];
    int s0 = e0 & ((1u << SRC_BITS) - 1), s1 = e1 & ((1u << SRC_BITS) - 1);
    int s2 = e2 & ((1u << SRC_BITS) - 1), s3 = e3 & ((1u << SRC_BITS) - 1);
    float f0 = feat[(size_t)s0 * 64 + lane];
    float f1 = feat[(size_t)s1 * 64 + lane];
    float f2 = feat[(size_t)s2 * 64 + lane];
    float f3 = feat[(size_t)s3 * 64 + lane];
    float w0 = dinv[s0], w1 = dinv[s1], w2 = dinv[s2], w3 = dinv[s3];
    unsafeAtomicAdd(&sacc[(e0 >> SRC_BITS) * 64 + lane], f0 * w0);
    unsafeAtomicAdd(&sacc[(e1 >> SRC_BITS) * 64 + lane], f1 * w1);
    unsafeAtomicAdd(&sacc[(e2 >> SRC_BITS) * 64 + lane], f2 * w2);
    unsafeAtomicAdd(&sacc[(e3 >> SRC_BITS) * 64 + lane], f3 * w3);
  }
  for (; j < je; ++j) {
    unsigned int e = tmp[j];
    int s = e & ((1u << SRC_BITS) - 1);
    unsafeAtomicAdd(&sacc[(e >> SRC_BITS) * 64 + lane], feat[(size_t)s * 64 + lane] * dinv[s]);
  }
  __syncthreads();

  for (int r = w; r < BKT_NODES; r += 4) {
    int node = (bkt << BKT_SHIFT) + r;
    if (node >= n_nodes) break;
    float dn = dinv[node];
    float self = feat[(size_t)node * 64 + lane];
    float v = fmaf(sacc[r * 64 + lane], dn, fmaf(self, dn * dn, bias[lane]));
    if (relu) v = fmaxf(v, 0.f);
    out[(size_t)node * 64 + lane] = v;
  }
}

extern "C" void kernel_launch(void* const* d_in, const int* in_sizes, int n_in,
                              void* d_out, int out_size, void* d_ws, size_t ws_size,
                              hipStream_t stream) {
  const float* x    = (const float*)d_in[0];
  const int*   ei   = (const int*)d_in[1];
  const float* W1   = (const float*)d_in[2];
  const float* b1   = (const float*)d_in[3];
  const float* W2   = (const float*)d_in[4];
  const float* b2   = (const float*)d_in[5];
  const float* Wlin = (const float*)d_in[6];
  const float* blin = (const float*)d_in[7];
  float* out = (float*)d_out;

  const int n_nodes = in_sizes[0] / DIN;
  const int n_edges = in_sizes[1] / 2;
  const int* src = ei;
  const int* dst = ei + n_edges;
  const int nbkt = (n_nodes + BKT_NODES - 1) >> BKT_SHIFT;
  const int ntiles = (n_edges + TILE - 1) / TILE;

  char* ws = (char*)d_ws;
  const size_t featBytes = (size_t)n_nodes * DH * sizeof(float);
  size_t off = 0;
  auto alloc = [&](size_t bytes) {
    void* p = ws + off;
    off += (bytes + 255) & ~(size_t)255;
    return p;
  };
  float*        bufA     = (float*)alloc(featBytes);          // h1, then h2
  float*        bufB     = (float*)alloc(featBytes);          // h1r
  unsigned int* tmp      = (unsigned int*)alloc((size_t)n_edges * 4);  // packed edges
  float*        dinv     = (float*)alloc((size_t)n_nodes * 4);
  int*          gtot     = (int*)alloc((size_t)MAXBKT * 4);
  int*          gcur     = (int*)alloc((size_t)MAXBKT * 4);
  int*          boff     = (int*)alloc((size_t)(MAXBKT + 1) * 4);
  float*        Wc       = (float*)alloc(64 * 64 * 4);
  float*        bias_out = (float*)alloc(64 * 4);

  hipMemsetAsync(gtot, 0, (size_t)nbkt * 4, stream);

  k_wc<<<1, 256, 0, stream>>>(W2, b2, Wlin, blin, Wc, bias_out);
  k_cnt<<<ntiles, 256, 0, stream>>>(dst, n_edges, gtot, nbkt);
  k_bscan<<<1, 256, 0, stream>>>(gtot, nbkt, boff, gcur);
  k_bin<<<ntiles, 256, 0, stream>>>(src, dst, n_edges, gcur, tmp, nbkt);
  k_ddinv<<<nbkt, 256, 0, stream>>>(tmp, boff, dinv, n_nodes);

  const int gblocks = (n_nodes + 63) / 64;

  // layer 1
  k_gemm<<<gblocks, 256, 0, stream>>>(x, W1, bufA, n_nodes, DIN);
  k_gather<<<nbkt, 256, 0, stream>>>(bufA, tmp, boff, dinv, b1, bufB, n_nodes, 1);

  // layer 2 (+ folded final linear): h2 = h1r @ (W2@Wlin)
  k_gemm<<<gblocks, 256, 0, stream>>>(bufB, Wc, bufA, n_nodes, DH);
  k_gather<<<nbkt, 256, 0, stream>>>(bufA, tmp, boff, dinv, bias_out, out, n_nodes, 0);
}

// Round 5
// 773.896 us; speedup vs baseline: 4.0879x; 4.0879x over previous
//
#include <hip/hip_runtime.h>

#define DIN 512
#define DH  64
#define BKT_SHIFT 7                 // 128 nodes per bucket
#define BKT_NODES 128
#define MAXBKT 1024                 // supports up to 131072 nodes
#define TILE 8192                   // edges per binning workgroup
#define SRC_BITS 17                 // n_nodes < 131072
#define SRC_MASK ((1u << SRC_BITS) - 1)

// ---------------- small precompute: Wc = W2@Wlin, bias_out = b2@Wlin + blin ----
__global__ __launch_bounds__(256) void k_wc(const float* __restrict__ W2,
                                            const float* __restrict__ b2,
                                            const float* __restrict__ Wlin,
                                            const float* __restrict__ blin,
                                            float* __restrict__ Wc,
                                            float* __restrict__ bias_out) {
  int tid = threadIdx.x;
  for (int idx = tid; idx < 64 * 64; idx += 256) {
    int i = idx >> 6, j = idx & 63;
    float s = 0.f;
    #pragma unroll 8
    for (int k = 0; k < 64; ++k) s = fmaf(W2[i * 64 + k], Wlin[k * 64 + j], s);
    Wc[idx] = s;
  }
  if (tid < 64) {
    float s = blin[tid];
    #pragma unroll 8
    for (int k = 0; k < 64; ++k) s = fmaf(b2[k], Wlin[k * 64 + tid], s);
    bias_out[tid] = s;
  }
}

// ---------------- pass 0: per-bucket edge counts (tile-aggregated) ------------
__global__ __launch_bounds__(256) void k_cnt(const int* __restrict__ dst, int n_edges,
                                             int* __restrict__ gtot, int nbkt) {
  __shared__ int cnt[MAXBKT];
  for (int b = threadIdx.x; b < nbkt; b += 256) cnt[b] = 0;
  __syncthreads();
  int e0 = blockIdx.x * TILE;
  int e1 = min(e0 + TILE, n_edges);
  for (int e = e0 + threadIdx.x; e < e1; e += 256)
    atomicAdd(&cnt[dst[e] >> BKT_SHIFT], 1);
  __syncthreads();
  for (int b = threadIdx.x; b < nbkt; b += 256) {
    int c = cnt[b];
    if (c) atomicAdd(&gtot[b], c);
  }
}

// ------- scan bucket counts -> boff[0..nbkt], gcur; also rowptr[n_nodes] ------
__global__ __launch_bounds__(256) void k_bscan(const int* __restrict__ gtot, int nbkt,
                                               int* __restrict__ boff,
                                               int* __restrict__ gcur,
                                               int* __restrict__ rowptr_n) {
  __shared__ int sh[256];
  int t = threadIdx.x;
  int base = t * 4;
  int v[4];
  int s = 0;
  #pragma unroll
  for (int k = 0; k < 4; ++k) {
    int i = base + k;
    v[k] = (i < nbkt) ? gtot[i] : 0;
    s += v[k];
  }
  sh[t] = s;
  __syncthreads();
  for (int off = 1; off < 256; off <<= 1) {
    int x = sh[t];
    int y = (t >= off) ? sh[t - off] : 0;
    __syncthreads();
    sh[t] = x + y;
    __syncthreads();
  }
  int excl = sh[t] - s;
  #pragma unroll
  for (int k = 0; k < 4; ++k) {
    int i = base + k;
    if (i < nbkt) { boff[i] = excl; gcur[i] = excl; }
    excl += v[k];
  }
  if (t == 255) {
    boff[nbkt] = sh[255];
    *rowptr_n = sh[255];   // rowptr[n_nodes] = total edges
  }
}

// ---------------- pass 1: bin edges into buckets, 4B packed entries -----------
__global__ __launch_bounds__(256) void k_bin(const int* __restrict__ src,
                                             const int* __restrict__ dst, int n_edges,
                                             int* __restrict__ gcur,
                                             unsigned int* __restrict__ tmp, int nbkt) {
  __shared__ int cnt[MAXBKT];
  __shared__ int base[MAXBKT];
  int t = threadIdx.x;
  for (int b = t; b < nbkt; b += 256) cnt[b] = 0;
  __syncthreads();
  int e0 = blockIdx.x * TILE;
  int e1 = min(e0 + TILE, n_edges);
  for (int e = e0 + t; e < e1; e += 256)
    atomicAdd(&cnt[dst[e] >> BKT_SHIFT], 1);
  __syncthreads();
  for (int b = t; b < nbkt; b += 256) {
    int c = cnt[b];
    base[b] = c ? atomicAdd(&gcur[b], c) : 0;
    cnt[b] = 0;
  }
  __syncthreads();
  for (int e = e0 + t; e < e1; e += 256) {
    int d = dst[e];
    int bkt = d >> BKT_SHIFT;
    int off = atomicAdd(&cnt[bkt], 1);
    tmp[base[bkt] + off] =
        (unsigned int)src[e] | ((unsigned int)(d & (BKT_NODES - 1)) << SRC_BITS);
  }
}

// ------- per-bucket: node degrees (LDS), scan -> rowptr, dinv -----------------
__global__ __launch_bounds__(256) void k_nodeptr(const unsigned int* __restrict__ tmp,
                                                 const int* __restrict__ boff,
                                                 int* __restrict__ rowptr,
                                                 float* __restrict__ dinv, int n_nodes) {
  __shared__ int cnt[BKT_NODES];
  __shared__ int sc[BKT_NODES];
  const int t = threadIdx.x;
  const int bkt = blockIdx.x;
  if (t < BKT_NODES) cnt[t] = 0;
  __syncthreads();
  const int beg = boff[bkt], end = boff[bkt + 1];
  for (int j = beg + t; j < end; j += 256)
    atomicAdd(&cnt[tmp[j] >> SRC_BITS], 1);
  __syncthreads();
  int v = (t < BKT_NODES) ? cnt[t] : 0;
  if (t < BKT_NODES) sc[t] = v;
  __syncthreads();
  for (int off = 1; off < BKT_NODES; off <<= 1) {
    int x = 0, y = 0;
    if (t < BKT_NODES) { x = sc[t]; y = (t >= off) ? sc[t - off] : 0; }
    __syncthreads();
    if (t < BKT_NODES) sc[t] = x + y;
    __syncthreads();
  }
  if (t < BKT_NODES) {
    int node = (bkt << BKT_SHIFT) + t;
    if (node < n_nodes) {
      rowptr[node] = beg + sc[t] - v;            // exclusive
      dinv[node] = rsqrtf((float)(v + 1));       // +1 self loop
    }
  }
}

// ------- per-bucket place: tmp -> per-node CSR pairs {src, w} (LDS cursors) ---
__global__ __launch_bounds__(256) void k_place(const unsigned int* __restrict__ tmp,
                                               const int* __restrict__ boff,
                                               const float* __restrict__ dinv,
                                               int2* __restrict__ pairs, int n_nodes) {
  __shared__ int cnt[BKT_NODES];
  __shared__ int sc[BKT_NODES];
  const int t = threadIdx.x;
  const int bkt = blockIdx.x;
  if (t < BKT_NODES) cnt[t] = 0;
  __syncthreads();
  const int beg = boff[bkt], end = boff[bkt + 1];
  for (int j = beg + t; j < end; j += 256)
    atomicAdd(&cnt[tmp[j] >> SRC_BITS], 1);
  __syncthreads();
  int v = (t < BKT_NODES) ? cnt[t] : 0;
  if (t < BKT_NODES) sc[t] = v;
  __syncthreads();
  for (int off = 1; off < BKT_NODES; off <<= 1) {
    int x = 0, y = 0;
    if (t < BKT_NODES) { x = sc[t]; y = (t >= off) ? sc[t - off] : 0; }
    __syncthreads();
    if (t < BKT_NODES) sc[t] = x + y;
    __syncthreads();
  }
  if (t < BKT_NODES) cnt[t] = sc[t] - v;  // cnt becomes LDS cursor (exclusive)
  __syncthreads();
  for (int j = beg + t; j < end; j += 256) {
    unsigned int e = tmp[j];
    int r = e >> SRC_BITS;
    int s = e & SRC_MASK;
    int node = (bkt << BKT_SHIFT) + r;
    int pos = atomicAdd(&cnt[r], 1);
    float w = dinv[s] * dinv[node];
    pairs[beg + pos] = make_int2(s, __float_as_int(w));
  }
}

// ---------------- fp32 tiled GEMM: C[M,64] = A[M,K] @ B[K,64] -----------------
__global__ __launch_bounds__(256) void k_gemm(const float* __restrict__ A,
                                              const float* __restrict__ B,
                                              float* __restrict__ C,
                                              int M, int K) {
  __shared__ float As[16][68];
  __shared__ float Bs[16][64];
  const int tid = threadIdx.x;
  const int block_m = blockIdx.x * 64;
  const int tm = (tid >> 4) * 4;
  const int tn = (tid & 15) * 4;
  const int lm = tid >> 2;
  const int lk = (tid & 3) * 4;
  const int bk = tid >> 4;
  const int bn = (tid & 15) * 4;

  float acc[4][4] = {{0.f}};

  for (int k0 = 0; k0 < K; k0 += 16) {
    float4 a = make_float4(0.f, 0.f, 0.f, 0.f);
    int an = block_m + lm;
    if (an < M) a = *(const float4*)&A[(size_t)an * K + k0 + lk];
    As[lk + 0][lm] = a.x;
    As[lk + 1][lm] = a.y;
    As[lk + 2][lm] = a.z;
    As[lk + 3][lm] = a.w;
    *(float4*)&Bs[bk][bn] = *(const float4*)&B[(size_t)(k0 + bk) * 64 + bn];
    __syncthreads();
    #pragma unroll
    for (int k = 0; k < 16; ++k) {
      float4 av = *(const float4*)&As[k][tm];
      float4 bv = *(const float4*)&Bs[k][tn];
      acc[0][0] = fmaf(av.x, bv.x, acc[0][0]);
      acc[0][1] = fmaf(av.x, bv.y, acc[0][1]);
      acc[0][2] = fmaf(av.x, bv.z, acc[0][2]);
      acc[0][3] = fmaf(av.x, bv.w, acc[0][3]);
      acc[1][0] = fmaf(av.y, bv.x, acc[1][0]);
      acc[1][1] = fmaf(av.y, bv.y, acc[1][1]);
      acc[1][2] = fmaf(av.y, bv.z, acc[1][2]);
      acc[1][3] = fmaf(av.y, bv.w, acc[1][3]);
      acc[2][0] = fmaf(av.z, bv.x, acc[2][0]);
      acc[2][1] = fmaf(av.z, bv.y, acc[2][1]);
      acc[2][2] = fmaf(av.z, bv.z, acc[2][2]);
      acc[2][3] = fmaf(av.z, bv.w, acc[2][3]);
      acc[3][0] = fmaf(av.w, bv.x, acc[3][0]);
      acc[3][1] = fmaf(av.w, bv.y, acc[3][1]);
      acc[3][2] = fmaf(av.w, bv.z, acc[3][2]);
      acc[3][3] = fmaf(av.w, bv.w, acc[3][3]);
    }
    __syncthreads();
  }
  #pragma unroll
  for (int i = 0; i < 4; ++i) {
    int row = block_m + tm + i;
    if (row < M) {
      float4 r = make_float4(acc[i][0], acc[i][1], acc[i][2], acc[i][3]);
      *(float4*)&C[(size_t)row * 64 + tn] = r;
    }
  }
}

// ---- per-node-wave CSR gather + fused self-loop/bias/ReLU --------------------
// out[n,l] = act( sum_e w_e*feat[s_e,l] + dinv[n]^2*feat[n,l] + bias[l] )
__global__ __launch_bounds__(256) void k_gather(const float* __restrict__ feat,
                                                const int* __restrict__ rowptr,
                                                const int2* __restrict__ pairs,
                                                const float* __restrict__ dinv,
                                                const float* __restrict__ bias,
                                                float* __restrict__ out,
                                                int n_nodes, int relu) {
  int node = blockIdx.x * 4 + (threadIdx.x >> 6);
  int lane = threadIdx.x & 63;
  if (node >= n_nodes) return;
  int beg = rowptr[node], end = rowptr[node + 1];
  float acc = 0.f;
  int j = beg;
  for (; j + 4 <= end; j += 4) {
    int2 p0 = pairs[j], p1 = pairs[j + 1], p2 = pairs[j + 2], p3 = pairs[j + 3];
    float f0 = feat[(size_t)p0.x * 64 + lane];
    float f1 = feat[(size_t)p1.x * 64 + lane];
    float f2 = feat[(size_t)p2.x * 64 + lane];
    float f3 = feat[(size_t)p3.x * 64 + lane];
    acc = fmaf(f0, __int_as_float(p0.y), acc);
    acc = fmaf(f1, __int_as_float(p1.y), acc);
    acc = fmaf(f2, __int_as_float(p2.y), acc);
    acc = fmaf(f3, __int_as_float(p3.y), acc);
  }
  for (; j < end; ++j) {
    int2 p = pairs[j];
    acc = fmaf(feat[(size_t)p.x * 64 + lane], __int_as_float(p.y), acc);
  }
  float dn = dinv[node];
  float self = feat[(size_t)node * 64 + lane];
  float v = fmaf(self, dn * dn, acc) + bias[lane];
  if (relu) v = fmaxf(v, 0.f);
  out[(size_t)node * 64 + lane] = v;
}

extern "C" void kernel_launch(void* const* d_in, const int* in_sizes, int n_in,
                              void* d_out, int out_size, void* d_ws, size_t ws_size,
                              hipStream_t stream) {
  const float* x    = (const float*)d_in[0];
  const int*   ei   = (const int*)d_in[1];
  const float* W1   = (const float*)d_in[2];
  const float* b1   = (const float*)d_in[3];
  const float* W2   = (const float*)d_in[4];
  const float* b2   = (const float*)d_in[5];
  const float* Wlin = (const float*)d_in[6];
  const float* blin = (const float*)d_in[7];
  float* out = (float*)d_out;

  const int n_nodes = in_sizes[0] / DIN;
  const int n_edges = in_sizes[1] / 2;
  const int* src = ei;
  const int* dst = ei + n_edges;
  const int nbkt = (n_nodes + BKT_NODES - 1) >> BKT_SHIFT;
  const int ntiles = (n_edges + TILE - 1) / TILE;

  char* ws = (char*)d_ws;
  const size_t featBytes = (size_t)n_nodes * DH * sizeof(float);
  size_t off = 0;
  auto alloc = [&](size_t bytes) {
    void* p = ws + off;
    off += (bytes + 255) & ~(size_t)255;
    return p;
  };
  float*        bufA     = (float*)alloc(featBytes);                   // h1, h2
  float*        bufB     = (float*)alloc(featBytes);                   // h1r
  unsigned int* tmp      = (unsigned int*)alloc((size_t)n_edges * 4);  // bucketed
  int2*         pairs    = (int2*)alloc((size_t)n_edges * 8);          // CSR {src,w}
  float*        dinv     = (float*)alloc((size_t)n_nodes * 4);
  int*          rowptr   = (int*)alloc(((size_t)n_nodes + 1) * 4);
  int*          gtot     = (int*)alloc((size_t)MAXBKT * 4);
  int*          gcur     = (int*)alloc((size_t)MAXBKT * 4);
  int*          boff     = (int*)alloc((size_t)(MAXBKT + 1) * 4);
  float*        Wc       = (float*)alloc(64 * 64 * 4);
  float*        bias_out = (float*)alloc(64 * 4);

  hipMemsetAsync(gtot, 0, (size_t)nbkt * 4, stream);

  k_wc<<<1, 256, 0, stream>>>(W2, b2, Wlin, blin, Wc, bias_out);
  k_cnt<<<ntiles, 256, 0, stream>>>(dst, n_edges, gtot, nbkt);
  k_bscan<<<1, 256, 0, stream>>>(gtot, nbkt, boff, gcur, rowptr + n_nodes);
  k_bin<<<ntiles, 256, 0, stream>>>(src, dst, n_edges, gcur, tmp, nbkt);
  k_nodeptr<<<nbkt, 256, 0, stream>>>(tmp, boff, rowptr, dinv, n_nodes);
  k_place<<<nbkt, 256, 0, stream>>>(tmp, boff, dinv, pairs, n_nodes);

  const int gblocks = (n_nodes + 63) / 64;
  const int agblocks = (n_nodes + 3) / 4;

  // layer 1
  k_gemm<<<gblocks, 256, 0, stream>>>(x, W1, bufA, n_nodes, DIN);
  k_gather<<<agblocks, 256, 0, stream>>>(bufA, rowptr, pairs, dinv, b1, bufB, n_nodes, 1);

  // layer 2 (+ folded final linear): h2 = h1r @ (W2@Wlin)
  k_gemm<<<gblocks, 256, 0, stream>>>(bufB, Wc, bufA, n_nodes, DH);
  k_gather<<<agblocks, 256, 0, stream>>>(bufA, rowptr, pairs, dinv, bias_out, out, n_nodes, 0);
}

// Round 6
// 757.366 us; speedup vs baseline: 4.1771x; 1.0218x over previous
//
#include <hip/hip_runtime.h>
#include <hip/hip_fp16.h>

#define DIN 512
#define DH  64
#define BKT_SHIFT 10                // 1024 nodes per bucket
#define BKT_NODES 1024
#define MAXBKT 128                  // supports up to 131072 nodes
#define TILE 8192                   // edges per binning workgroup
#define SRC_BITS 17                 // n_nodes < 131072
#define SRC_MASK ((1u << SRC_BITS) - 1)

// ---------------- small precompute: Wc = W2@Wlin, bias_out = b2@Wlin + blin ----
__global__ __launch_bounds__(256) void k_wc(const float* __restrict__ W2,
                                            const float* __restrict__ b2,
                                            const float* __restrict__ Wlin,
                                            const float* __restrict__ blin,
                                            float* __restrict__ Wc,
                                            float* __restrict__ bias_out) {
  int tid = threadIdx.x;
  for (int idx = tid; idx < 64 * 64; idx += 256) {
    int i = idx >> 6, j = idx & 63;
    float s = 0.f;
    #pragma unroll 8
    for (int k = 0; k < 64; ++k) s = fmaf(W2[i * 64 + k], Wlin[k * 64 + j], s);
    Wc[idx] = s;
  }
  if (tid < 64) {
    float s = blin[tid];
    #pragma unroll 8
    for (int k = 0; k < 64; ++k) s = fmaf(b2[k], Wlin[k * 64 + tid], s);
    bias_out[tid] = s;
  }
}

// ---------------- pass 0: per-bucket edge counts (tile-aggregated) ------------
__global__ __launch_bounds__(256) void k_cnt(const int* __restrict__ dst, int n_edges,
                                             int* __restrict__ gtot, int nbkt) {
  __shared__ int cnt[MAXBKT];
  for (int b = threadIdx.x; b < nbkt; b += 256) cnt[b] = 0;
  __syncthreads();
  int e0 = blockIdx.x * TILE;
  int e1 = min(e0 + TILE, n_edges);
  for (int e = e0 + threadIdx.x; e < e1; e += 256)
    atomicAdd(&cnt[dst[e] >> BKT_SHIFT], 1);
  __syncthreads();
  for (int b = threadIdx.x; b < nbkt; b += 256) {
    int c = cnt[b];
    if (c) atomicAdd(&gtot[b], c);
  }
}

// ------- scan bucket counts -> boff[0..nbkt], gcur; also rowptr[n_nodes] ------
__global__ __launch_bounds__(256) void k_bscan(const int* __restrict__ gtot, int nbkt,
                                               int* __restrict__ boff,
                                               int* __restrict__ gcur,
                                               int* __restrict__ rowptr_n) {
  __shared__ int sh[256];
  int t = threadIdx.x;
  int v = (t < nbkt) ? gtot[t] : 0;
  sh[t] = v;
  __syncthreads();
  for (int off = 1; off < 256; off <<= 1) {
    int x = sh[t];
    int y = (t >= off) ? sh[t - off] : 0;
    __syncthreads();
    sh[t] = x + y;
    __syncthreads();
  }
  if (t < nbkt) {
    int excl = sh[t] - v;
    boff[t] = excl;
    gcur[t] = excl;
  }
  if (t == 255) {
    boff[nbkt] = sh[255];
    *rowptr_n = sh[255];
  }
}

// ---------------- pass 1: bin edges into buckets, 4B packed entries -----------
__global__ __launch_bounds__(256) void k_bin(const int* __restrict__ src,
                                             const int* __restrict__ dst, int n_edges,
                                             int* __restrict__ gcur,
                                             unsigned int* __restrict__ tmp, int nbkt) {
  __shared__ int cnt[MAXBKT];
  __shared__ int base[MAXBKT];
  int t = threadIdx.x;
  for (int b = t; b < nbkt; b += 256) cnt[b] = 0;
  __syncthreads();
  int e0 = blockIdx.x * TILE;
  int e1 = min(e0 + TILE, n_edges);
  for (int e = e0 + t; e < e1; e += 256)
    atomicAdd(&cnt[dst[e] >> BKT_SHIFT], 1);
  __syncthreads();
  for (int b = t; b < nbkt; b += 256) {
    int c = cnt[b];
    base[b] = c ? atomicAdd(&gcur[b], c) : 0;
    cnt[b] = 0;
  }
  __syncthreads();
  for (int e = e0 + t; e < e1; e += 256) {
    int d = dst[e];
    int bkt = d >> BKT_SHIFT;
    int off = atomicAdd(&cnt[bkt], 1);
    tmp[base[bkt] + off] =
        (unsigned int)src[e] | ((unsigned int)(d & (BKT_NODES - 1)) << SRC_BITS);
  }
}

// ------- fused per-bucket: degrees -> rowptr/dinv, then place srcs (4B) -------
__global__ __launch_bounds__(256) void k_place(const unsigned int* __restrict__ tmp,
                                               const int* __restrict__ boff,
                                               int* __restrict__ rowptr,
                                               float* __restrict__ dinv,
                                               int* __restrict__ srcs, int n_nodes) {
  __shared__ int cnt[BKT_NODES];   // histogram -> cursor
  __shared__ int sh[256];
  const int t = threadIdx.x;
  const int bkt = blockIdx.x;
  #pragma unroll
  for (int k = 0; k < BKT_NODES / 256; ++k) cnt[t + 256 * k] = 0;
  __syncthreads();
  const int beg = boff[bkt], end = boff[bkt + 1];
  for (int j = beg + t; j < end; j += 256)
    atomicAdd(&cnt[tmp[j] >> SRC_BITS], 1);
  __syncthreads();
  // scan cnt[0..1023] exclusive: 4 contiguous per thread + block scan of sums
  int v[4];
  int s = 0;
  const int base = t * 4;
  #pragma unroll
  for (int k = 0; k < 4; ++k) {
    v[k] = cnt[base + k];
    s += v[k];
  }
  sh[t] = s;
  __syncthreads();
  for (int off = 1; off < 256; off <<= 1) {
    int x = sh[t];
    int y = (t >= off) ? sh[t - off] : 0;
    __syncthreads();
    sh[t] = x + y;
    __syncthreads();
  }
  int excl = sh[t] - s;
  #pragma unroll
  for (int k = 0; k < 4; ++k) {
    int idx = base + k;
    int node = (bkt << BKT_SHIFT) + idx;
    if (node < n_nodes) {
      rowptr[node] = beg + excl;
      dinv[node] = rsqrtf((float)(v[k] + 1));   // +1 self loop
    }
    cnt[idx] = excl;     // exclusive bucket-local cursor
    excl += v[k];
  }
  __syncthreads();
  for (int j = beg + t; j < end; j += 256) {
    unsigned int e = tmp[j];
    int r = e >> SRC_BITS;
    int pos = atomicAdd(&cnt[r], 1);
    srcs[beg + pos] = (int)(e & SRC_MASK);
  }
}

// ---------------- fp32 tiled GEMM: C[M,64] = A[M,K] @ B[K,64], + fp16 copy ----
__global__ __launch_bounds__(256) void k_gemm(const float* __restrict__ A,
                                              const float* __restrict__ B,
                                              float* __restrict__ C,
                                              __half* __restrict__ Ch,
                                              int M, int K) {
  __shared__ float As[16][68];
  __shared__ float Bs[16][64];
  const int tid = threadIdx.x;
  const int block_m = blockIdx.x * 64;
  const int tm = (tid >> 4) * 4;
  const int tn = (tid & 15) * 4;
  const int lm = tid >> 2;
  const int lk = (tid & 3) * 4;
  const int bk = tid >> 4;
  const int bn = (tid & 15) * 4;

  float acc[4][4] = {{0.f}};

  for (int k0 = 0; k0 < K; k0 += 16) {
    float4 a = make_float4(0.f, 0.f, 0.f, 0.f);
    int an = block_m + lm;
    if (an < M) a = *(const float4*)&A[(size_t)an * K + k0 + lk];
    As[lk + 0][lm] = a.x;
    As[lk + 1][lm] = a.y;
    As[lk + 2][lm] = a.z;
    As[lk + 3][lm] = a.w;
    *(float4*)&Bs[bk][bn] = *(const float4*)&B[(size_t)(k0 + bk) * 64 + bn];
    __syncthreads();
    #pragma unroll
    for (int k = 0; k < 16; ++k) {
      float4 av = *(const float4*)&As[k][tm];
      float4 bv = *(const float4*)&Bs[k][tn];
      acc[0][0] = fmaf(av.x, bv.x, acc[0][0]);
      acc[0][1] = fmaf(av.x, bv.y, acc[0][1]);
      acc[0][2] = fmaf(av.x, bv.z, acc[0][2]);
      acc[0][3] = fmaf(av.x, bv.w, acc[0][3]);
      acc[1][0] = fmaf(av.y, bv.x, acc[1][0]);
      acc[1][1] = fmaf(av.y, bv.y, acc[1][1]);
      acc[1][2] = fmaf(av.y, bv.z, acc[1][2]);
      acc[1][3] = fmaf(av.y, bv.w, acc[1][3]);
      acc[2][0] = fmaf(av.z, bv.x, acc[2][0]);
      acc[2][1] = fmaf(av.z, bv.y, acc[2][1]);
      acc[2][2] = fmaf(av.z, bv.z, acc[2][2]);
      acc[2][3] = fmaf(av.z, bv.w, acc[2][3]);
      acc[3][0] = fmaf(av.w, bv.x, acc[3][0]);
      acc[3][1] = fmaf(av.w, bv.y, acc[3][1]);
      acc[3][2] = fmaf(av.w, bv.z, acc[3][2]);
      acc[3][3] = fmaf(av.w, bv.w, acc[3][3]);
    }
    __syncthreads();
  }
  #pragma unroll
  for (int i = 0; i < 4; ++i) {
    int row = block_m + tm + i;
    if (row < M) {
      float4 r = make_float4(acc[i][0], acc[i][1], acc[i][2], acc[i][3]);
      *(float4*)&C[(size_t)row * 64 + tn] = r;
      *(__half2*)&Ch[(size_t)row * 64 + tn]     = __floats2half2_rn(r.x, r.y);
      *(__half2*)&Ch[(size_t)row * 64 + tn + 2] = __floats2half2_rn(r.z, r.w);
    }
  }
}

// ---- per-node-wave CSR gather (fp16 feat) + fused self-loop/bias/ReLU --------
// out[n,l] = act( dinv[n]*( sum_e dinv[s_e]*feat[s_e,l] + dinv[n]*feat[n,l] ) + bias[l] )
__global__ __launch_bounds__(256) void k_gather(const __half* __restrict__ feath,
                                                const int* __restrict__ rowptr,
                                                const int* __restrict__ srcs,
                                                const float* __restrict__ dinv,
                                                const float* __restrict__ bias,
                                                float* __restrict__ out,
                                                int n_nodes, int relu) {
  int node = blockIdx.x * 4 + (threadIdx.x >> 6);
  int lane = threadIdx.x & 63;
  if (node >= n_nodes) return;
  int beg = rowptr[node], end = rowptr[node + 1];
  float acc = 0.f;
  int j = beg;
  for (; j + 4 <= end; j += 4) {
    int s0 = srcs[j], s1 = srcs[j + 1], s2 = srcs[j + 2], s3 = srcs[j + 3];
    float f0 = __half2float(feath[(size_t)s0 * 64 + lane]);
    float f1 = __half2float(feath[(size_t)s1 * 64 + lane]);
    float f2 = __half2float(feath[(size_t)s2 * 64 + lane]);
    float f3 = __half2float(feath[(size_t)s3 * 64 + lane]);
    float w0 = dinv[s0], w1 = dinv[s1], w2 = dinv[s2], w3 = dinv[s3];
    acc = fmaf(f0, w0, acc);
    acc = fmaf(f1, w1, acc);
    acc = fmaf(f2, w2, acc);
    acc = fmaf(f3, w3, acc);
  }
  for (; j < end; ++j) {
    int s = srcs[j];
    acc = fmaf(__half2float(feath[(size_t)s * 64 + lane]), dinv[s], acc);
  }
  float dn = dinv[node];
  float self = __half2float(feath[(size_t)node * 64 + lane]);
  float v = fmaf(fmaf(self, dn, acc), dn, bias[lane]);
  if (relu) v = fmaxf(v, 0.f);
  out[(size_t)node * 64 + lane] = v;
}

extern "C" void kernel_launch(void* const* d_in, const int* in_sizes, int n_in,
                              void* d_out, int out_size, void* d_ws, size_t ws_size,
                              hipStream_t stream) {
  const float* x    = (const float*)d_in[0];
  const int*   ei   = (const int*)d_in[1];
  const float* W1   = (const float*)d_in[2];
  const float* b1   = (const float*)d_in[3];
  const float* W2   = (const float*)d_in[4];
  const float* b2   = (const float*)d_in[5];
  const float* Wlin = (const float*)d_in[6];
  const float* blin = (const float*)d_in[7];
  float* out = (float*)d_out;

  const int n_nodes = in_sizes[0] / DIN;
  const int n_edges = in_sizes[1] / 2;
  const int* src = ei;
  const int* dst = ei + n_edges;
  const int nbkt = (n_nodes + BKT_NODES - 1) >> BKT_SHIFT;
  const int ntiles = (n_edges + TILE - 1) / TILE;

  char* ws = (char*)d_ws;
  const size_t featBytes = (size_t)n_nodes * DH * sizeof(float);
  size_t off = 0;
  auto alloc = [&](size_t bytes) {
    void* p = ws + off;
    off += (bytes + 255) & ~(size_t)255;
    return p;
  };
  float*        bufA     = (float*)alloc(featBytes);                   // h1, h2
  float*        bufB     = (float*)alloc(featBytes);                   // h1r
  unsigned int* tmp      = (unsigned int*)alloc((size_t)n_edges * 4);  // bucketed; reused as feath
  int*          srcs     = (int*)alloc((size_t)n_edges * 4);           // CSR src list
  float*        dinv     = (float*)alloc((size_t)n_nodes * 4);
  int*          rowptr   = (int*)alloc(((size_t)n_nodes + 1) * 4);
  int*          gtot     = (int*)alloc((size_t)MAXBKT * 4);
  int*          gcur     = (int*)alloc((size_t)MAXBKT * 4);
  int*          boff     = (int*)alloc((size_t)(MAXBKT + 1) * 4);
  float*        Wc       = (float*)alloc(64 * 64 * 4);
  float*        bias_out = (float*)alloc(64 * 4);
  __half*       feath    = (__half*)alloc((size_t)n_nodes * DH * 2);   // fp16 feat copy

  hipMemsetAsync(gtot, 0, (size_t)nbkt * 4, stream);

  k_wc<<<1, 256, 0, stream>>>(W2, b2, Wlin, blin, Wc, bias_out);
  k_cnt<<<ntiles, 256, 0, stream>>>(dst, n_edges, gtot, nbkt);
  k_bscan<<<1, 256, 0, stream>>>(gtot, nbkt, boff, gcur, rowptr + n_nodes);
  k_bin<<<ntiles, 256, 0, stream>>>(src, dst, n_edges, gcur, tmp, nbkt);
  k_place<<<nbkt, 256, 0, stream>>>(tmp, boff, rowptr, dinv, srcs, n_nodes);

  const int gblocks = (n_nodes + 63) / 64;
  const int agblocks = (n_nodes + 3) / 4;

  // layer 1
  k_gemm<<<gblocks, 256, 0, stream>>>(x, W1, bufA, feath, n_nodes, DIN);
  k_gather<<<agblocks, 256, 0, stream>>>(feath, rowptr, srcs, dinv, b1, bufB, n_nodes, 1);

  // layer 2 (+ folded final linear): h2 = h1r @ (W2@Wlin)
  k_gemm<<<gblocks, 256, 0, stream>>>(bufB, Wc, bufA, feath, n_nodes, DH);
  k_gather<<<agblocks, 256, 0, stream>>>(feath, rowptr, srcs, dinv, bias_out, out, n_nodes, 0);
}

// Round 7
// 749.758 us; speedup vs baseline: 4.2195x; 1.0101x over previous
//
#include <hip/hip_runtime.h>

#define DIN 512
#define DH  64
#define BKT_SHIFT 10                // 1024 nodes per bucket
#define BKT_NODES 1024
#define MAXBKT 128                  // supports up to 131072 nodes
#define TILE 8192                   // edges per binning workgroup
#define SRC_BITS 17                 // n_nodes < 131072
#define SRC_MASK ((1u << SRC_BITS) - 1)

typedef __attribute__((ext_vector_type(8))) _Float16 half8_t;
typedef __attribute__((ext_vector_type(4))) float float4_t;

// ---- prep: Wc=W2@Wlin -> Wct fp16 [n][k]; bias_out=b2@Wlin+blin; Wt fp16 [n][k]=W1^T
__global__ __launch_bounds__(256) void k_prep(const float* __restrict__ W1,
                                              const float* __restrict__ W2,
                                              const float* __restrict__ b2,
                                              const float* __restrict__ Wlin,
                                              const float* __restrict__ blin,
                                              _Float16* __restrict__ Wt,
                                              _Float16* __restrict__ Wct,
                                              float* __restrict__ bias_out) {
  __shared__ float WcS[64 * 64];
  const int tid = threadIdx.x;
  for (int idx = tid; idx < 64 * 64; idx += 256) {
    int i = idx >> 6, j = idx & 63;
    float s = 0.f;
    #pragma unroll 8
    for (int k = 0; k < 64; ++k) s = fmaf(W2[i * 64 + k], Wlin[k * 64 + j], s);
    WcS[idx] = s;
  }
  if (tid < 64) {
    float s = blin[tid];
    #pragma unroll 8
    for (int k = 0; k < 64; ++k) s = fmaf(b2[k], Wlin[k * 64 + tid], s);
    bias_out[tid] = s;
  }
  // Wt[n][k] = (fp16) W1[k][n], written as half8 granules, coalesced
  for (int G = tid; G < 64 * 512 / 8; G += 256) {
    int n = G >> 6, k = (G & 63) * 8;
    half8_t h;
    #pragma unroll
    for (int j = 0; j < 8; ++j) h[j] = (_Float16)W1[(size_t)(k + j) * 64 + n];
    *(half8_t*)&Wt[(size_t)n * 512 + k] = h;
  }
  __syncthreads();
  // Wct[n][k] = (fp16) Wc[k][n]
  for (int G = tid; G < 64 * 64 / 8; G += 256) {
    int n = G >> 3, k = (G & 7) * 8;
    half8_t h;
    #pragma unroll
    for (int j = 0; j < 8; ++j) h[j] = (_Float16)WcS[(k + j) * 64 + n];
    *(half8_t*)&Wct[(size_t)n * 64 + k] = h;
  }
}

// ---------------- pass 0: per-bucket edge counts (tile-aggregated) ------------
__global__ __launch_bounds__(256) void k_cnt(const int* __restrict__ dst, int n_edges,
                                             int* __restrict__ gtot, int nbkt) {
  __shared__ int cnt[MAXBKT];
  for (int b = threadIdx.x; b < nbkt; b += 256) cnt[b] = 0;
  __syncthreads();
  int e0 = blockIdx.x * TILE;
  int e1 = min(e0 + TILE, n_edges);
  for (int e = e0 + threadIdx.x; e < e1; e += 256)
    atomicAdd(&cnt[dst[e] >> BKT_SHIFT], 1);
  __syncthreads();
  for (int b = threadIdx.x; b < nbkt; b += 256) {
    int c = cnt[b];
    if (c) atomicAdd(&gtot[b], c);
  }
}

// ------- scan bucket counts -> boff[0..nbkt], gcur ----------------------------
__global__ __launch_bounds__(256) void k_bscan(const int* __restrict__ gtot, int nbkt,
                                               int* __restrict__ boff,
                                               int* __restrict__ gcur,
                                               int* __restrict__ rowptr_n) {
  __shared__ int sh[256];
  int t = threadIdx.x;
  int v = (t < nbkt) ? gtot[t] : 0;
  sh[t] = v;
  __syncthreads();
  for (int off = 1; off < 256; off <<= 1) {
    int x = sh[t];
    int y = (t >= off) ? sh[t - off] : 0;
    __syncthreads();
    sh[t] = x + y;
    __syncthreads();
  }
  if (t < nbkt) {
    int excl = sh[t] - v;
    boff[t] = excl;
    gcur[t] = excl;
  }
  if (t == 255) {
    boff[nbkt] = sh[255];
    *rowptr_n = sh[255];
  }
}

// ---------------- pass 1: bin edges into buckets, 4B packed entries -----------
__global__ __launch_bounds__(256) void k_bin(const int* __restrict__ src,
                                             const int* __restrict__ dst, int n_edges,
                                             int* __restrict__ gcur,
                                             unsigned int* __restrict__ tmp, int nbkt) {
  __shared__ int cnt[MAXBKT];
  __shared__ int base[MAXBKT];
  int t = threadIdx.x;
  for (int b = t; b < nbkt; b += 256) cnt[b] = 0;
  __syncthreads();
  int e0 = blockIdx.x * TILE;
  int e1 = min(e0 + TILE, n_edges);
  for (int e = e0 + t; e < e1; e += 256)
    atomicAdd(&cnt[dst[e] >> BKT_SHIFT], 1);
  __syncthreads();
  for (int b = t; b < nbkt; b += 256) {
    int c = cnt[b];
    base[b] = c ? atomicAdd(&gcur[b], c) : 0;
    cnt[b] = 0;
  }
  __syncthreads();
  for (int e = e0 + t; e < e1; e += 256) {
    int d = dst[e];
    int bkt = d >> BKT_SHIFT;
    int off = atomicAdd(&cnt[bkt], 1);
    tmp[base[bkt] + off] =
        (unsigned int)src[e] | ((unsigned int)(d & (BKT_NODES - 1)) << SRC_BITS);
  }
}

// ------- fused per-bucket: degrees -> rowptr/dinv, then place srcs (4B) -------
__global__ __launch_bounds__(256) void k_place(const unsigned int* __restrict__ tmp,
                                               const int* __restrict__ boff,
                                               int* __restrict__ rowptr,
                                               float* __restrict__ dinv,
                                               int* __restrict__ srcs, int n_nodes) {
  __shared__ int cnt[BKT_NODES];
  __shared__ int sh[256];
  const int t = threadIdx.x;
  const int bkt = blockIdx.x;
  #pragma unroll
  for (int k = 0; k < BKT_NODES / 256; ++k) cnt[t + 256 * k] = 0;
  __syncthreads();
  const int beg = boff[bkt], end = boff[bkt + 1];
  for (int j = beg + t; j < end; j += 256)
    atomicAdd(&cnt[tmp[j] >> SRC_BITS], 1);
  __syncthreads();
  int v[4];
  int s = 0;
  const int base = t * 4;
  #pragma unroll
  for (int k = 0; k < 4; ++k) {
    v[k] = cnt[base + k];
    s += v[k];
  }
  sh[t] = s;
  __syncthreads();
  for (int off = 1; off < 256; off <<= 1) {
    int x = sh[t];
    int y = (t >= off) ? sh[t - off] : 0;
    __syncthreads();
    sh[t] = x + y;
    __syncthreads();
  }
  int excl = sh[t] - s;
  #pragma unroll
  for (int k = 0; k < 4; ++k) {
    int idx = base + k;
    int node = (bkt << BKT_SHIFT) + idx;
    if (node < n_nodes) {
      rowptr[node] = beg + excl;
      dinv[node] = rsqrtf((float)(v[k] + 1));
    }
    cnt[idx] = excl;
    excl += v[k];
  }
  __syncthreads();
  for (int j = beg + t; j < end; j += 256) {
    unsigned int e = tmp[j];
    int r = e >> SRC_BITS;
    int pos = atomicAdd(&cnt[r], 1);
    srcs[beg + pos] = (int)(e & SRC_MASK);
  }
}

// ---------------- MFMA fp16 GEMM: Ch[M,64] = (fp16) A[M,KDIM] @ Bt^T ----------
// Bt is [64][KDIM] fp16 (already transposed). One wave = 16 rows x 64 cols.
// LDS swizzle: granule g (8 halves) of row n stored at g ^ (n&7)  -> 2-way free.
template <int KDIM, bool A_HALF>
__global__ __launch_bounds__(256) void k_mfma(const void* __restrict__ Ain,
                                              const _Float16* __restrict__ Bt,
                                              _Float16* __restrict__ Ch, int M) {
  __shared__ _Float16 Bs[64 * KDIM];  // 64KB (K=512) / 8KB (K=64)
  const int tid = threadIdx.x;
  // stage Bt -> LDS (swizzled)
  for (int G = tid; G < 8 * KDIM; G += 256) {
    int n = G / (KDIM / 8);
    int g = G % (KDIM / 8);
    half8_t h = *(const half8_t*)&Bt[(size_t)G * 8];
    *(half8_t*)&Bs[n * KDIM + ((g ^ (n & 7)) * 8)] = h;
  }
  __syncthreads();

  const int wave = tid >> 6, lane = tid & 63;
  const int quad = lane >> 4, lrow = lane & 15;
  const int row = blockIdx.x * 64 + wave * 16 + lrow;
  const int rowc = min(row, M - 1);

  float4_t acc[4] = {{0.f, 0.f, 0.f, 0.f}, {0.f, 0.f, 0.f, 0.f},
                     {0.f, 0.f, 0.f, 0.f}, {0.f, 0.f, 0.f, 0.f}};

  #pragma unroll
  for (int k0 = 0; k0 < KDIM; k0 += 32) {
    half8_t a;
    if (A_HALF) {
      a = *(const half8_t*)((const _Float16*)Ain + (size_t)rowc * KDIM + k0 + quad * 8);
    } else {
      const float* Af = (const float*)Ain + (size_t)rowc * KDIM + k0 + quad * 8;
      float4 x0 = *(const float4*)Af;
      float4 x1 = *(const float4*)(Af + 4);
      a[0] = (_Float16)x0.x; a[1] = (_Float16)x0.y;
      a[2] = (_Float16)x0.z; a[3] = (_Float16)x0.w;
      a[4] = (_Float16)x1.x; a[5] = (_Float16)x1.y;
      a[6] = (_Float16)x1.z; a[7] = (_Float16)x1.w;
    }
    const int g = (k0 >> 3) + quad;
    #pragma unroll
    for (int nb = 0; nb < 4; ++nb) {
      int n = nb * 16 + lrow;
      half8_t b = *(const half8_t*)&Bs[n * KDIM + ((g ^ (n & 7)) * 8)];
      acc[nb] = __builtin_amdgcn_mfma_f32_16x16x32_f16(a, b, acc[nb], 0, 0, 0);
    }
  }

  // epilogue: repack via LDS (reuse Bs) -> coalesced fp16 stores
  __syncthreads();
  _Float16* scratch = Bs + wave * 1024;  // 16x64 halves per wave
  #pragma unroll
  for (int nb = 0; nb < 4; ++nb)
    #pragma unroll
    for (int r = 0; r < 4; ++r)
      scratch[(quad * 4 + r) * 64 + nb * 16 + lrow] = (_Float16)acc[nb][r];
  // wave-private region: no cross-wave barrier needed
  const int r2 = lane >> 2, c2 = (lane & 3) * 16;
  const int row_out = blockIdx.x * 64 + wave * 16 + r2;
  half8_t o0 = *(const half8_t*)&scratch[r2 * 64 + c2];
  half8_t o1 = *(const half8_t*)&scratch[r2 * 64 + c2 + 8];
  if (row_out < M) {
    *(half8_t*)&Ch[(size_t)row_out * 64 + c2] = o0;
    *(half8_t*)&Ch[(size_t)row_out * 64 + c2 + 8] = o1;
  }
}

// ---- per-node-wave CSR gather (fp16 feat) + fused self-loop/bias (+ReLU) -----
// out = act( dinv[n]*( sum_e dinv[s_e]*feat[s_e,l] + dinv[n]*feat[n,l] ) + bias[l] )
// outh != nullptr -> fp16 output (with ReLU); else fp32 output (no ReLU)
__global__ __launch_bounds__(256) void k_gather(const _Float16* __restrict__ feath,
                                                const int* __restrict__ rowptr,
                                                const int* __restrict__ srcs,
                                                const float* __restrict__ dinv,
                                                const float* __restrict__ bias,
                                                _Float16* __restrict__ outh,
                                                float* __restrict__ outf,
                                                int n_nodes) {
  int node = blockIdx.x * 4 + (threadIdx.x >> 6);
  int lane = threadIdx.x & 63;
  if (node >= n_nodes) return;
  int beg = rowptr[node], end = rowptr[node + 1];
  float acc = 0.f;
  int j = beg;
  for (; j + 4 <= end; j += 4) {
    int s0 = srcs[j], s1 = srcs[j + 1], s2 = srcs[j + 2], s3 = srcs[j + 3];
    float f0 = (float)feath[(size_t)s0 * 64 + lane];
    float f1 = (float)feath[(size_t)s1 * 64 + lane];
    float f2 = (float)feath[(size_t)s2 * 64 + lane];
    float f3 = (float)feath[(size_t)s3 * 64 + lane];
    float w0 = dinv[s0], w1 = dinv[s1], w2 = dinv[s2], w3 = dinv[s3];
    acc = fmaf(f0, w0, acc);
    acc = fmaf(f1, w1, acc);
    acc = fmaf(f2, w2, acc);
    acc = fmaf(f3, w3, acc);
  }
  for (; j < end; ++j) {
    int s = srcs[j];
    acc = fmaf((float)feath[(size_t)s * 64 + lane], dinv[s], acc);
  }
  float dn = dinv[node];
  float self = (float)feath[(size_t)node * 64 + lane];
  float v = fmaf(fmaf(self, dn, acc), dn, bias[lane]);
  if (outh) {
    v = fmaxf(v, 0.f);  // ReLU fused on layer-1 path
    outh[(size_t)node * 64 + lane] = (_Float16)v;
  } else {
    outf[(size_t)node * 64 + lane] = v;
  }
}

extern "C" void kernel_launch(void* const* d_in, const int* in_sizes, int n_in,
                              void* d_out, int out_size, void* d_ws, size_t ws_size,
                              hipStream_t stream) {
  const float* x    = (const float*)d_in[0];
  const int*   ei   = (const int*)d_in[1];
  const float* W1   = (const float*)d_in[2];
  const float* b1   = (const float*)d_in[3];
  const float* W2   = (const float*)d_in[4];
  const float* b2   = (const float*)d_in[5];
  const float* Wlin = (const float*)d_in[6];
  const float* blin = (const float*)d_in[7];
  float* out = (float*)d_out;

  const int n_nodes = in_sizes[0] / DIN;
  const int n_edges = in_sizes[1] / 2;
  const int* src = ei;
  const int* dst = ei + n_edges;
  const int nbkt = (n_nodes + BKT_NODES - 1) >> BKT_SHIFT;
  const int ntiles = (n_edges + TILE - 1) / TILE;

  char* ws = (char*)d_ws;
  size_t off = 0;
  auto alloc = [&](size_t bytes) {
    void* p = ws + off;
    off += (bytes + 255) & ~(size_t)255;
    return p;
  };
  const size_t featH = (size_t)n_nodes * DH * 2;
  _Float16*     feath1   = (_Float16*)alloc(featH);                    // h1 fp16
  _Float16*     h1r      = (_Float16*)alloc(featH);                    // relu'd, fp16
  _Float16*     feath2   = (_Float16*)alloc(featH);                    // h2 fp16
  unsigned int* tmp      = (unsigned int*)alloc((size_t)n_edges * 4);  // bucketed
  int*          srcs     = (int*)alloc((size_t)n_edges * 4);           // CSR src list
  float*        dinv     = (float*)alloc((size_t)n_nodes * 4);
  int*          rowptr   = (int*)alloc(((size_t)n_nodes + 1) * 4);
  int*          gtot     = (int*)alloc((size_t)MAXBKT * 4);
  int*          gcur     = (int*)alloc((size_t)MAXBKT * 4);
  int*          boff     = (int*)alloc((size_t)(MAXBKT + 1) * 4);
  _Float16*     Wt       = (_Float16*)alloc(64 * 512 * 2);             // W1^T fp16
  _Float16*     Wct      = (_Float16*)alloc(64 * 64 * 2);              // (W2@Wlin)^T fp16
  float*        bias_out = (float*)alloc(64 * 4);

  hipMemsetAsync(gtot, 0, (size_t)nbkt * 4, stream);

  k_prep<<<1, 256, 0, stream>>>(W1, W2, b2, Wlin, blin, Wt, Wct, bias_out);
  k_cnt<<<ntiles, 256, 0, stream>>>(dst, n_edges, gtot, nbkt);
  k_bscan<<<1, 256, 0, stream>>>(gtot, nbkt, boff, gcur, rowptr + n_nodes);
  k_bin<<<ntiles, 256, 0, stream>>>(src, dst, n_edges, gcur, tmp, nbkt);
  k_place<<<nbkt, 256, 0, stream>>>(tmp, boff, rowptr, dinv, srcs, n_nodes);

  const int gblocks = (n_nodes + 63) / 64;
  const int agblocks = (n_nodes + 3) / 4;

  // layer 1: h1 = x @ W1 (fp16 MFMA), gather -> h1r (fp16, ReLU fused)
  k_mfma<512, false><<<gblocks, 256, 0, stream>>>(x, Wt, feath1, n_nodes);
  k_gather<<<agblocks, 256, 0, stream>>>(feath1, rowptr, srcs, dinv, b1, h1r, nullptr, n_nodes);

  // layer 2 (+ folded final linear): h2 = h1r @ (W2@Wlin), gather -> out (fp32)
  k_mfma<64, true><<<gblocks, 256, 0, stream>>>(h1r, Wct, feath2, n_nodes);
  k_gather<<<agblocks, 256, 0, stream>>>(feath2, rowptr, srcs, dinv, bias_out, nullptr, out, n_nodes);
}

// Round 8
// 663.838 us; speedup vs baseline: 4.7656x; 1.1294x over previous
//
#include <hip/hip_runtime.h>

#define DIN 512
#define DH  64
#define BKT_SHIFT 10                // 1024 nodes per bucket
#define BKT_NODES 1024
#define MAXBKT 128                  // supports up to 131072 nodes
#define TILE 8192                   // edges per binning workgroup
#define SRC_BITS 17                 // n_nodes < 131072
#define SRC_MASK ((1u << SRC_BITS) - 1)

typedef __attribute__((ext_vector_type(8))) _Float16 half8_t;
typedef __attribute__((ext_vector_type(4))) _Float16 half4_t;
typedef __attribute__((ext_vector_type(4))) float float4_t;

// ---- prep: Wc=W2@Wlin -> Wct fp16 [n][k]; bias_out=b2@Wlin+blin; Wt fp16 [n][k]=W1^T
__global__ __launch_bounds__(256) void k_prep(const float* __restrict__ W1,
                                              const float* __restrict__ W2,
                                              const float* __restrict__ b2,
                                              const float* __restrict__ Wlin,
                                              const float* __restrict__ blin,
                                              _Float16* __restrict__ Wt,
                                              _Float16* __restrict__ Wct,
                                              float* __restrict__ bias_out) {
  __shared__ float WcS[64 * 64];
  const int tid = threadIdx.x;
  for (int idx = tid; idx < 64 * 64; idx += 256) {
    int i = idx >> 6, j = idx & 63;
    float s = 0.f;
    #pragma unroll 8
    for (int k = 0; k < 64; ++k) s = fmaf(W2[i * 64 + k], Wlin[k * 64 + j], s);
    WcS[idx] = s;
  }
  if (tid < 64) {
    float s = blin[tid];
    #pragma unroll 8
    for (int k = 0; k < 64; ++k) s = fmaf(b2[k], Wlin[k * 64 + tid], s);
    bias_out[tid] = s;
  }
  for (int G = tid; G < 64 * 512 / 8; G += 256) {
    int n = G >> 6, k = (G & 63) * 8;
    half8_t h;
    #pragma unroll
    for (int j = 0; j < 8; ++j) h[j] = (_Float16)W1[(size_t)(k + j) * 64 + n];
    *(half8_t*)&Wt[(size_t)n * 512 + k] = h;
  }
  __syncthreads();
  for (int G = tid; G < 64 * 64 / 8; G += 256) {
    int n = G >> 3, k = (G & 7) * 8;
    half8_t h;
    #pragma unroll
    for (int j = 0; j < 8; ++j) h[j] = (_Float16)WcS[(k + j) * 64 + n];
    *(half8_t*)&Wct[(size_t)n * 64 + k] = h;
  }
}

// ---------------- pass 0: per-bucket edge counts (tile-aggregated) ------------
__global__ __launch_bounds__(256) void k_cnt(const int* __restrict__ dst, int n_edges,
                                             int* __restrict__ gtot, int nbkt) {
  __shared__ int cnt[MAXBKT];
  for (int b = threadIdx.x; b < nbkt; b += 256) cnt[b] = 0;
  __syncthreads();
  int e0 = blockIdx.x * TILE;
  int e1 = min(e0 + TILE, n_edges);
  for (int e = e0 + threadIdx.x; e < e1; e += 256)
    atomicAdd(&cnt[dst[e] >> BKT_SHIFT], 1);
  __syncthreads();
  for (int b = threadIdx.x; b < nbkt; b += 256) {
    int c = cnt[b];
    if (c) atomicAdd(&gtot[b], c);
  }
}

// ------- scan bucket counts -> boff[0..nbkt], gcur ----------------------------
__global__ __launch_bounds__(256) void k_bscan(const int* __restrict__ gtot, int nbkt,
                                               int* __restrict__ boff,
                                               int* __restrict__ gcur,
                                               int* __restrict__ rowptr_n) {
  __shared__ int sh[256];
  int t = threadIdx.x;
  int v = (t < nbkt) ? gtot[t] : 0;
  sh[t] = v;
  __syncthreads();
  for (int off = 1; off < 256; off <<= 1) {
    int x = sh[t];
    int y = (t >= off) ? sh[t - off] : 0;
    __syncthreads();
    sh[t] = x + y;
    __syncthreads();
  }
  if (t < nbkt) {
    int excl = sh[t] - v;
    boff[t] = excl;
    gcur[t] = excl;
  }
  if (t == 255) {
    boff[nbkt] = sh[255];
    *rowptr_n = sh[255];
  }
}

// ---------------- pass 1: bin edges into buckets, 4B packed entries -----------
__global__ __launch_bounds__(256) void k_bin(const int* __restrict__ src,
                                             const int* __restrict__ dst, int n_edges,
                                             int* __restrict__ gcur,
                                             unsigned int* __restrict__ tmp, int nbkt) {
  __shared__ int cnt[MAXBKT];
  __shared__ int base[MAXBKT];
  int t = threadIdx.x;
  for (int b = t; b < nbkt; b += 256) cnt[b] = 0;
  __syncthreads();
  int e0 = blockIdx.x * TILE;
  int e1 = min(e0 + TILE, n_edges);
  for (int e = e0 + t; e < e1; e += 256)
    atomicAdd(&cnt[dst[e] >> BKT_SHIFT], 1);
  __syncthreads();
  for (int b = t; b < nbkt; b += 256) {
    int c = cnt[b];
    base[b] = c ? atomicAdd(&gcur[b], c) : 0;
    cnt[b] = 0;
  }
  __syncthreads();
  for (int e = e0 + t; e < e1; e += 256) {
    int d = dst[e];
    int bkt = d >> BKT_SHIFT;
    int off = atomicAdd(&cnt[bkt], 1);
    tmp[base[bkt] + off] =
        (unsigned int)src[e] | ((unsigned int)(d & (BKT_NODES - 1)) << SRC_BITS);
  }
}

// ------- fused per-bucket: degrees -> rowptr/dinv, then place srcs (4B) -------
__global__ __launch_bounds__(256) void k_place(const unsigned int* __restrict__ tmp,
                                               const int* __restrict__ boff,
                                               int* __restrict__ rowptr,
                                               float* __restrict__ dinv,
                                               int* __restrict__ srcs, int n_nodes) {
  __shared__ int cnt[BKT_NODES];
  __shared__ int sh[256];
  const int t = threadIdx.x;
  const int bkt = blockIdx.x;
  #pragma unroll
  for (int k = 0; k < BKT_NODES / 256; ++k) cnt[t + 256 * k] = 0;
  __syncthreads();
  const int beg = boff[bkt], end = boff[bkt + 1];
  for (int j = beg + t; j < end; j += 256)
    atomicAdd(&cnt[tmp[j] >> SRC_BITS], 1);
  __syncthreads();
  int v[4];
  int s = 0;
  const int base = t * 4;
  #pragma unroll
  for (int k = 0; k < 4; ++k) {
    v[k] = cnt[base + k];
    s += v[k];
  }
  sh[t] = s;
  __syncthreads();
  for (int off = 1; off < 256; off <<= 1) {
    int x = sh[t];
    int y = (t >= off) ? sh[t - off] : 0;
    __syncthreads();
    sh[t] = x + y;
    __syncthreads();
  }
  int excl = sh[t] - s;
  #pragma unroll
  for (int k = 0; k < 4; ++k) {
    int idx = base + k;
    int node = (bkt << BKT_SHIFT) + idx;
    if (node < n_nodes) {
      rowptr[node] = beg + excl;
      dinv[node] = rsqrtf((float)(v[k] + 1));
    }
    cnt[idx] = excl;
    excl += v[k];
  }
  __syncthreads();
  for (int j = beg + t; j < end; j += 256) {
    unsigned int e = tmp[j];
    int r = e >> SRC_BITS;
    int pos = atomicAdd(&cnt[r], 1);
    srcs[beg + pos] = (int)(e & SRC_MASK);
  }
}

// ---------------- MFMA fp16 GEMM: Ch[M,64] = (fp16) A[M,KDIM] @ Bt^T ----------
// 1024 threads = 16 waves, 256 rows/block. Bt [64][KDIM] fp16, LDS-swizzled.
template <int KDIM, bool A_HALF>
__global__ __launch_bounds__(1024) void k_mfma(const void* __restrict__ Ain,
                                               const _Float16* __restrict__ Bt,
                                               _Float16* __restrict__ Ch, int M) {
  constexpr int BS_HALVES = (64 * KDIM > 16384) ? 64 * KDIM : 16384;
  __shared__ _Float16 Bs[BS_HALVES];  // 64KB (K=512) / 32KB (K=64)
  const int tid = threadIdx.x;
  for (int G = tid; G < 8 * KDIM; G += 1024) {
    int n = G / (KDIM / 8);
    int g = G % (KDIM / 8);
    half8_t h = *(const half8_t*)&Bt[(size_t)G * 8];
    *(half8_t*)&Bs[n * KDIM + ((g ^ (n & 7)) * 8)] = h;
  }
  __syncthreads();

  const int wave = tid >> 6, lane = tid & 63;
  const int quad = lane >> 4, lrow = lane & 15;
  const int row = blockIdx.x * 256 + wave * 16 + lrow;
  const int rowc = min(row, M - 1);

  float4_t acc[4] = {{0.f, 0.f, 0.f, 0.f}, {0.f, 0.f, 0.f, 0.f},
                     {0.f, 0.f, 0.f, 0.f}, {0.f, 0.f, 0.f, 0.f}};

  #pragma unroll
  for (int k0 = 0; k0 < KDIM; k0 += 32) {
    half8_t a;
    if (A_HALF) {
      a = *(const half8_t*)((const _Float16*)Ain + (size_t)rowc * KDIM + k0 + quad * 8);
    } else {
      const float* Af = (const float*)Ain + (size_t)rowc * KDIM + k0 + quad * 8;
      float4 x0 = *(const float4*)Af;
      float4 x1 = *(const float4*)(Af + 4);
      a[0] = (_Float16)x0.x; a[1] = (_Float16)x0.y;
      a[2] = (_Float16)x0.z; a[3] = (_Float16)x0.w;
      a[4] = (_Float16)x1.x; a[5] = (_Float16)x1.y;
      a[6] = (_Float16)x1.z; a[7] = (_Float16)x1.w;
    }
    const int g = (k0 >> 3) + quad;
    #pragma unroll
    for (int nb = 0; nb < 4; ++nb) {
      int n = nb * 16 + lrow;
      half8_t b = *(const half8_t*)&Bs[n * KDIM + ((g ^ (n & 7)) * 8)];
      acc[nb] = __builtin_amdgcn_mfma_f32_16x16x32_f16(a, b, acc[nb], 0, 0, 0);
    }
  }

  __syncthreads();
  _Float16* scratch = Bs + wave * 1024;  // 16x64 halves per wave (32KB total, fits)
  #pragma unroll
  for (int nb = 0; nb < 4; ++nb)
    #pragma unroll
    for (int r = 0; r < 4; ++r)
      scratch[(quad * 4 + r) * 64 + nb * 16 + lrow] = (_Float16)acc[nb][r];
  const int r2 = lane >> 2, c2 = (lane & 3) * 16;
  const int row_out = blockIdx.x * 256 + wave * 16 + r2;
  half8_t o0 = *(const half8_t*)&scratch[r2 * 64 + c2];
  half8_t o1 = *(const half8_t*)&scratch[r2 * 64 + c2 + 8];
  if (row_out < M) {
    *(half8_t*)&Ch[(size_t)row_out * 64 + c2] = o0;
    *(half8_t*)&Ch[(size_t)row_out * 64 + c2 + 8] = o1;
  }
}

// ---- per-node-wave CSR gather, 4 edges/step (half4 per lane) -----------------
// lane = 16*esub + cg; lane covers channels 4cg..4cg+3 of edge slot esub.
// out = act( dinv[n]*( sum_e dinv[s_e]*feat[s_e,:] + dinv[n]*feat[n,:] ) + bias )
__global__ __launch_bounds__(256) void k_gather(const _Float16* __restrict__ feath,
                                                const int* __restrict__ rowptr,
                                                const int* __restrict__ srcs,
                                                const float* __restrict__ dinv,
                                                const float* __restrict__ bias,
                                                _Float16* __restrict__ outh,
                                                float* __restrict__ outf,
                                                int n_nodes) {
  int node = blockIdx.x * 4 + (threadIdx.x >> 6);
  int lane = threadIdx.x & 63;
  if (node >= n_nodes) return;
  const int esub = lane >> 4;
  const int cg4 = (lane & 15) * 4;
  const int beg = rowptr[node], end = rowptr[node + 1];
  float4 acc = make_float4(0.f, 0.f, 0.f, 0.f);
  int j = beg;
  for (; j + 8 <= end; j += 8) {
    int s0 = srcs[j + esub];
    int s1 = srcs[j + 4 + esub];
    float w0 = dinv[s0], w1 = dinv[s1];
    half4_t f0 = *(const half4_t*)&feath[(size_t)s0 * 64 + cg4];
    half4_t f1 = *(const half4_t*)&feath[(size_t)s1 * 64 + cg4];
    acc.x = fmaf((float)f0[0], w0, acc.x);
    acc.y = fmaf((float)f0[1], w0, acc.y);
    acc.z = fmaf((float)f0[2], w0, acc.z);
    acc.w = fmaf((float)f0[3], w0, acc.w);
    acc.x = fmaf((float)f1[0], w1, acc.x);
    acc.y = fmaf((float)f1[1], w1, acc.y);
    acc.z = fmaf((float)f1[2], w1, acc.z);
    acc.w = fmaf((float)f1[3], w1, acc.w);
  }
  for (; j < end; j += 4) {
    int idx = j + esub;
    bool act = idx < end;
    int s = srcs[act ? idx : beg];
    float w = act ? dinv[s] : 0.f;
    half4_t f = *(const half4_t*)&feath[(size_t)s * 64 + cg4];
    acc.x = fmaf((float)f[0], w, acc.x);
    acc.y = fmaf((float)f[1], w, acc.y);
    acc.z = fmaf((float)f[2], w, acc.z);
    acc.w = fmaf((float)f[3], w, acc.w);
  }
  // reduce across the 4 edge slots (lanes differing in bits 4,5)
  #pragma unroll
  for (int m = 16; m <= 32; m <<= 1) {
    acc.x += __shfl_xor(acc.x, m, 64);
    acc.y += __shfl_xor(acc.y, m, 64);
    acc.z += __shfl_xor(acc.z, m, 64);
    acc.w += __shfl_xor(acc.w, m, 64);
  }
  if (esub == 0) {
    float dn = dinv[node];
    half4_t sf = *(const half4_t*)&feath[(size_t)node * 64 + cg4];
    float4 bv = *(const float4*)&bias[cg4];
    float4 v;
    v.x = fmaf(fmaf((float)sf[0], dn, acc.x), dn, bv.x);
    v.y = fmaf(fmaf((float)sf[1], dn, acc.y), dn, bv.y);
    v.z = fmaf(fmaf((float)sf[2], dn, acc.z), dn, bv.z);
    v.w = fmaf(fmaf((float)sf[3], dn, acc.w), dn, bv.w);
    if (outh) {
      half4_t o;
      o[0] = (_Float16)fmaxf(v.x, 0.f);
      o[1] = (_Float16)fmaxf(v.y, 0.f);
      o[2] = (_Float16)fmaxf(v.z, 0.f);
      o[3] = (_Float16)fmaxf(v.w, 0.f);
      *(half4_t*)&outh[(size_t)node * 64 + cg4] = o;
    } else {
      *(float4*)&outf[(size_t)node * 64 + cg4] = v;
    }
  }
}

extern "C" void kernel_launch(void* const* d_in, const int* in_sizes, int n_in,
                              void* d_out, int out_size, void* d_ws, size_t ws_size,
                              hipStream_t stream) {
  const float* x    = (const float*)d_in[0];
  const int*   ei   = (const int*)d_in[1];
  const float* W1   = (const float*)d_in[2];
  const float* b1   = (const float*)d_in[3];
  const float* W2   = (const float*)d_in[4];
  const float* b2   = (const float*)d_in[5];
  const float* Wlin = (const float*)d_in[6];
  const float* blin = (const float*)d_in[7];
  float* out = (float*)d_out;

  const int n_nodes = in_sizes[0] / DIN;
  const int n_edges = in_sizes[1] / 2;
  const int* src = ei;
  const int* dst = ei + n_edges;
  const int nbkt = (n_nodes + BKT_NODES - 1) >> BKT_SHIFT;
  const int ntiles = (n_edges + TILE - 1) / TILE;

  char* ws = (char*)d_ws;
  size_t off = 0;
  auto alloc = [&](size_t bytes) {
    void* p = ws + off;
    off += (bytes + 255) & ~(size_t)255;
    return p;
  };
  const size_t featH = (size_t)n_nodes * DH * 2;
  _Float16*     feath1   = (_Float16*)alloc(featH);
  _Float16*     h1r      = (_Float16*)alloc(featH);
  _Float16*     feath2   = (_Float16*)alloc(featH);
  unsigned int* tmp      = (unsigned int*)alloc((size_t)n_edges * 4);
  int*          srcs     = (int*)alloc((size_t)n_edges * 4);
  float*        dinv     = (float*)alloc((size_t)n_nodes * 4);
  int*          rowptr   = (int*)alloc(((size_t)n_nodes + 1) * 4);
  int*          gtot     = (int*)alloc((size_t)MAXBKT * 4);
  int*          gcur     = (int*)alloc((size_t)MAXBKT * 4);
  int*          boff     = (int*)alloc((size_t)(MAXBKT + 1) * 4);
  _Float16*     Wt       = (_Float16*)alloc(64 * 512 * 2);
  _Float16*     Wct      = (_Float16*)alloc(64 * 64 * 2);
  float*        bias_out = (float*)alloc(64 * 4);

  hipMemsetAsync(gtot, 0, (size_t)nbkt * 4, stream);

  k_prep<<<1, 256, 0, stream>>>(W1, W2, b2, Wlin, blin, Wt, Wct, bias_out);
  k_cnt<<<ntiles, 256, 0, stream>>>(dst, n_edges, gtot, nbkt);
  k_bscan<<<1, 256, 0, stream>>>(gtot, nbkt, boff, gcur, rowptr + n_nodes);
  k_bin<<<ntiles, 256, 0, stream>>>(src, dst, n_edges, gcur, tmp, nbkt);
  k_place<<<nbkt, 256, 0, stream>>>(tmp, boff, rowptr, dinv, srcs, n_nodes);

  const int mblocks = (n_nodes + 255) / 256;
  const int agblocks = (n_nodes + 3) / 4;

  // layer 1: h1 = x @ W1 (fp16 MFMA), gather -> h1r (fp16, ReLU fused)
  k_mfma<512, false><<<mblocks, 1024, 0, stream>>>(x, Wt, feath1, n_nodes);
  k_gather<<<agblocks, 256, 0, stream>>>(feath1, rowptr, srcs, dinv, b1, h1r, nullptr, n_nodes);

  // layer 2 (+ folded final linear): h2 = h1r @ (W2@Wlin), gather -> out (fp32)
  k_mfma<64, true><<<mblocks, 1024, 0, stream>>>(h1r, Wct, feath2, n_nodes);
  k_gather<<<agblocks, 256, 0, stream>>>(feath2, rowptr, srcs, dinv, bias_out, nullptr, out, n_nodes);
}

// Round 9
// 598.877 us; speedup vs baseline: 5.2826x; 1.1085x over previous
//
#include <hip/hip_runtime.h>

#define DIN 512
#define DH  64
#define BKT_SHIFT 10                // 1024 nodes per bucket
#define BKT_NODES 1024
#define MAXBKT 128                  // supports up to 131072 nodes
#define TILE 8192                   // edges per binning workgroup
#define SRC_BITS 17                 // n_nodes < 131072
#define SRC_MASK ((1u << SRC_BITS) - 1)

typedef __attribute__((ext_vector_type(8))) _Float16 half8_t;
typedef __attribute__((ext_vector_type(4))) float float4_t;

// ---- prep (5 blocks):
//  block 0: Wc=W2@Wlin, bias_out=b2@Wlin+blin, Wct fp16 [n][k], gcur init
//  blocks 1..4: Wt fp16 [n][k] = W1^T slice via LDS transpose
__global__ __launch_bounds__(256) void k_prep(const float* __restrict__ W1,
                                              const float* __restrict__ W2,
                                              const float* __restrict__ b2,
                                              const float* __restrict__ Wlin,
                                              const float* __restrict__ blin,
                                              _Float16* __restrict__ Wt,
                                              _Float16* __restrict__ Wct,
                                              float* __restrict__ bias_out,
                                              int* __restrict__ gcur,
                                              int nbkt, int cap) {
  const int tid = threadIdx.x;
  if (blockIdx.x == 0) {
    __shared__ float WcS[64 * 64];
    for (int idx = tid; idx < 64 * 64; idx += 256) {
      int i = idx >> 6, j = idx & 63;
      float s = 0.f;
      #pragma unroll 8
      for (int k = 0; k < 64; ++k) s = fmaf(W2[i * 64 + k], Wlin[k * 64 + j], s);
      WcS[idx] = s;
    }
    if (tid < 64) {
      float s = blin[tid];
      #pragma unroll 8
      for (int k = 0; k < 64; ++k) s = fmaf(b2[k], Wlin[k * 64 + tid], s);
      bias_out[tid] = s;
    }
    for (int b = tid; b < nbkt; b += 256) gcur[b] = b * cap;
    __syncthreads();
    for (int G = tid; G < 64 * 64 / 8; G += 256) {
      int n = G >> 3, k = (G & 7) * 8;
      half8_t h;
      #pragma unroll
      for (int j = 0; j < 8; ++j) h[j] = (_Float16)WcS[(k + j) * 64 + n];
      *(half8_t*)&Wct[(size_t)n * 64 + k] = h;
    }
  } else {
    __shared__ _Float16 T[64][136];
    const int k0 = (blockIdx.x - 1) * 128;
    for (int idx = tid; idx < 128 * 64; idx += 256) {
      int kk = idx >> 6, n = idx & 63;
      T[n][kk] = (_Float16)W1[(size_t)(k0 + kk) * 64 + n];
    }
    __syncthreads();
    for (int G = tid; G < 64 * 16; G += 256) {
      int n = G >> 4, g = (G & 15) * 8;
      half8_t h = *(const half8_t*)&T[n][g];
      *(half8_t*)&Wt[(size_t)n * 512 + k0 + g] = h;
    }
  }
}

// ---- single-pass binning into fixed-capacity bucket regions ------------------
__global__ __launch_bounds__(256) void k_bin(const int* __restrict__ src,
                                             const int* __restrict__ dst, int n_edges,
                                             int* __restrict__ gcur,
                                             unsigned int* __restrict__ tmp,
                                             int nbkt, int cap) {
  __shared__ int cnt[MAXBKT];
  __shared__ int base[MAXBKT];
  int t = threadIdx.x;
  for (int b = t; b < nbkt; b += 256) cnt[b] = 0;
  __syncthreads();
  int e0 = blockIdx.x * TILE;
  int e1 = min(e0 + TILE, n_edges);
  for (int e = e0 + t; e < e1; e += 256)
    atomicAdd(&cnt[dst[e] >> BKT_SHIFT], 1);
  __syncthreads();
  for (int b = t; b < nbkt; b += 256) {
    int c = cnt[b];
    base[b] = c ? atomicAdd(&gcur[b], c) : 0;
    cnt[b] = 0;
  }
  __syncthreads();
  for (int e = e0 + t; e < e1; e += 256) {
    int d = dst[e];
    int bkt = d >> BKT_SHIFT;
    int off = atomicAdd(&cnt[bkt], 1);
    int pos = base[bkt] + off;
    if (pos < (bkt + 1) * cap)  // overflow guard (never hit for random dst)
      tmp[pos] = (unsigned int)src[e] | ((unsigned int)(d & (BKT_NODES - 1)) << SRC_BITS);
  }
}

// ------- per-bucket: degrees -> rowbeg/rowcnt/dinv, then place srcs (4B) ------
__global__ __launch_bounds__(256) void k_place(const unsigned int* __restrict__ tmp,
                                               const int* __restrict__ gcur,
                                               int* __restrict__ rowbeg,
                                               int* __restrict__ rowcnt,
                                               float* __restrict__ dinv,
                                               int* __restrict__ srcs,
                                               int n_nodes, int cap) {
  __shared__ int cnt[BKT_NODES];
  __shared__ int sh[256];
  const int t = threadIdx.x;
  const int bkt = blockIdx.x;
  #pragma unroll
  for (int k = 0; k < BKT_NODES / 256; ++k) cnt[t + 256 * k] = 0;
  __syncthreads();
  const int beg = bkt * cap;
  const int end = min(gcur[bkt], (bkt + 1) * cap);
  for (int j = beg + t; j < end; j += 256)
    atomicAdd(&cnt[tmp[j] >> SRC_BITS], 1);
  __syncthreads();
  int v[4];
  int s = 0;
  const int base = t * 4;
  #pragma unroll
  for (int k = 0; k < 4; ++k) {
    v[k] = cnt[base + k];
    s += v[k];
  }
  sh[t] = s;
  __syncthreads();
  for (int off = 1; off < 256; off <<= 1) {
    int x = sh[t];
    int y = (t >= off) ? sh[t - off] : 0;
    __syncthreads();
    sh[t] = x + y;
    __syncthreads();
  }
  int excl = sh[t] - s;
  #pragma unroll
  for (int k = 0; k < 4; ++k) {
    int idx = base + k;
    int node = (bkt << BKT_SHIFT) + idx;
    if (node < n_nodes) {
      rowbeg[node] = beg + excl;
      rowcnt[node] = v[k];
      dinv[node] = rsqrtf((float)(v[k] + 1));   // +1 self loop
    }
    cnt[idx] = excl;
    excl += v[k];
  }
  __syncthreads();
  for (int j = beg + t; j < end; j += 256) {
    unsigned int e = tmp[j];
    int r = e >> SRC_BITS;
    int pos = atomicAdd(&cnt[r], 1);
    srcs[beg + pos] = (int)(e & SRC_MASK);
  }
}

// ---------------- MFMA fp16 GEMM: Ch[M,64] = (fp16) A[M,KDIM] @ Bt^T ----------
// 1024 threads = 16 waves, 256 rows/block. Bt [64][KDIM] fp16, LDS-swizzled.
template <int KDIM, bool A_HALF>
__global__ __launch_bounds__(1024) void k_mfma(const void* __restrict__ Ain,
                                               const _Float16* __restrict__ Bt,
                                               _Float16* __restrict__ Ch, int M) {
  constexpr int BS_HALVES = (64 * KDIM > 16384) ? 64 * KDIM : 16384;
  __shared__ _Float16 Bs[BS_HALVES];  // 64KB (K=512) / 32KB (K=64)
  const int tid = threadIdx.x;
  for (int G = tid; G < 8 * KDIM; G += 1024) {
    int n = G / (KDIM / 8);
    int g = G % (KDIM / 8);
    half8_t h = *(const half8_t*)&Bt[(size_t)G * 8];
    *(half8_t*)&Bs[n * KDIM + ((g ^ (n & 7)) * 8)] = h;
  }
  __syncthreads();

  const int wave = tid >> 6, lane = tid & 63;
  const int quad = lane >> 4, lrow = lane & 15;
  const int row = blockIdx.x * 256 + wave * 16 + lrow;
  const int rowc = min(row, M - 1);

  float4_t acc[4] = {{0.f, 0.f, 0.f, 0.f}, {0.f, 0.f, 0.f, 0.f},
                     {0.f, 0.f, 0.f, 0.f}, {0.f, 0.f, 0.f, 0.f}};

  #pragma unroll
  for (int k0 = 0; k0 < KDIM; k0 += 32) {
    half8_t a;
    if (A_HALF) {
      a = *(const half8_t*)((const _Float16*)Ain + (size_t)rowc * KDIM + k0 + quad * 8);
    } else {
      const float* Af = (const float*)Ain + (size_t)rowc * KDIM + k0 + quad * 8;
      float4 x0 = *(const float4*)Af;
      float4 x1 = *(const float4*)(Af + 4);
      a[0] = (_Float16)x0.x; a[1] = (_Float16)x0.y;
      a[2] = (_Float16)x0.z; a[3] = (_Float16)x0.w;
      a[4] = (_Float16)x1.x; a[5] = (_Float16)x1.y;
      a[6] = (_Float16)x1.z; a[7] = (_Float16)x1.w;
    }
    const int g = (k0 >> 3) + quad;
    #pragma unroll
    for (int nb = 0; nb < 4; ++nb) {
      int n = nb * 16 + lrow;
      half8_t b = *(const half8_t*)&Bs[n * KDIM + ((g ^ (n & 7)) * 8)];
      acc[nb] = __builtin_amdgcn_mfma_f32_16x16x32_f16(a, b, acc[nb], 0, 0, 0);
    }
  }

  __syncthreads();
  _Float16* scratch = Bs + wave * 1024;  // 16x64 halves per wave
  #pragma unroll
  for (int nb = 0; nb < 4; ++nb)
    #pragma unroll
    for (int r = 0; r < 4; ++r)
      scratch[(quad * 4 + r) * 64 + nb * 16 + lrow] = (_Float16)acc[nb][r];
  const int r2 = lane >> 2, c2 = (lane & 3) * 16;
  const int row_out = blockIdx.x * 256 + wave * 16 + r2;
  half8_t o0 = *(const half8_t*)&scratch[r2 * 64 + c2];
  half8_t o1 = *(const half8_t*)&scratch[r2 * 64 + c2 + 8];
  if (row_out < M) {
    *(half8_t*)&Ch[(size_t)row_out * 64 + c2] = o0;
    *(half8_t*)&Ch[(size_t)row_out * 64 + c2 + 8] = o1;
  }
}

// ---- per-node-wave CSR gather, 8 edges/step (half8 per lane) -----------------
// lane = 8*esub + cg; lane covers channels 8cg..8cg+7 of edge slot esub (0..7).
// out = act( dinv[n]*( sum_e dinv[s_e]*feat[s_e,:] + dinv[n]*feat[n,:] ) + bias )
__global__ __launch_bounds__(256) void k_gather(const _Float16* __restrict__ feath,
                                                const int* __restrict__ rowbeg,
                                                const int* __restrict__ rowcnt,
                                                const int* __restrict__ srcs,
                                                const float* __restrict__ dinv,
                                                const float* __restrict__ bias,
                                                _Float16* __restrict__ outh,
                                                float* __restrict__ outf,
                                                int n_nodes) {
  int node = blockIdx.x * 4 + (threadIdx.x >> 6);
  int lane = threadIdx.x & 63;
  if (node >= n_nodes) return;
  const int esub = lane >> 3;       // 0..7 edge slot
  const int ch8 = (lane & 7) * 8;   // channel group base
  const int beg = rowbeg[node];
  const int end = beg + rowcnt[node];
  float acc[8] = {0.f, 0.f, 0.f, 0.f, 0.f, 0.f, 0.f, 0.f};
  int j = beg;
  for (; j + 16 <= end; j += 16) {
    int s0 = srcs[j + esub];
    int s1 = srcs[j + 8 + esub];
    float w0 = dinv[s0], w1 = dinv[s1];
    half8_t f0 = *(const half8_t*)&feath[(size_t)s0 * 64 + ch8];
    half8_t f1 = *(const half8_t*)&feath[(size_t)s1 * 64 + ch8];
    #pragma unroll
    for (int k = 0; k < 8; ++k) acc[k] = fmaf((float)f0[k], w0, acc[k]);
    #pragma unroll
    for (int k = 0; k < 8; ++k) acc[k] = fmaf((float)f1[k], w1, acc[k]);
  }
  for (; j < end; j += 8) {
    int idx = j + esub;
    bool act = idx < end;
    int s = srcs[act ? idx : beg];
    float w = act ? dinv[s] : 0.f;
    half8_t f = *(const half8_t*)&feath[(size_t)s * 64 + ch8];
    #pragma unroll
    for (int k = 0; k < 8; ++k) acc[k] = fmaf((float)f[k], w, acc[k]);
  }
  // reduce across the 8 edge slots (lane bits 3,4,5)
  #pragma unroll
  for (int m = 8; m <= 32; m <<= 1)
    #pragma unroll
    for (int k = 0; k < 8; ++k) acc[k] += __shfl_xor(acc[k], m, 64);
  if (esub == 0) {
    float dn = dinv[node];
    half8_t sf = *(const half8_t*)&feath[(size_t)node * 64 + ch8];
    float v[8];
    #pragma unroll
    for (int k = 0; k < 8; ++k)
      v[k] = fmaf(fmaf((float)sf[k], dn, acc[k]), dn, bias[ch8 + k]);
    if (outh) {
      half8_t o;
      #pragma unroll
      for (int k = 0; k < 8; ++k) o[k] = (_Float16)fmaxf(v[k], 0.f);
      *(half8_t*)&outh[(size_t)node * 64 + ch8] = o;
    } else {
      float4 o0 = make_float4(v[0], v[1], v[2], v[3]);
      float4 o1 = make_float4(v[4], v[5], v[6], v[7]);
      *(float4*)&outf[(size_t)node * 64 + ch8] = o0;
      *(float4*)&outf[(size_t)node * 64 + ch8 + 4] = o1;
    }
  }
}

extern "C" void kernel_launch(void* const* d_in, const int* in_sizes, int n_in,
                              void* d_out, int out_size, void* d_ws, size_t ws_size,
                              hipStream_t stream) {
  const float* x    = (const float*)d_in[0];
  const int*   ei   = (const int*)d_in[1];
  const float* W1   = (const float*)d_in[2];
  const float* b1   = (const float*)d_in[3];
  const float* W2   = (const float*)d_in[4];
  const float* b2   = (const float*)d_in[5];
  const float* Wlin = (const float*)d_in[6];
  const float* blin = (const float*)d_in[7];
  float* out = (float*)d_out;

  const int n_nodes = in_sizes[0] / DIN;
  const int n_edges = in_sizes[1] / 2;
  const int* src = ei;
  const int* dst = ei + n_edges;
  const int nbkt = (n_nodes + BKT_NODES - 1) >> BKT_SHIFT;
  const int ntiles = (n_edges + TILE - 1) / TILE;
  const int cap = ((n_edges / nbkt) * 5 / 4 + 1024 + 255) & ~255;  // bucket capacity

  char* ws = (char*)d_ws;
  size_t off = 0;
  auto alloc = [&](size_t bytes) {
    void* p = ws + off;
    off += (bytes + 255) & ~(size_t)255;
    return p;
  };
  const size_t featH = (size_t)n_nodes * DH * 2;
  const size_t padE = (size_t)nbkt * cap;
  _Float16*     feath1   = (_Float16*)alloc(featH);
  _Float16*     h1r      = (_Float16*)alloc(featH);
  _Float16*     feath2   = (_Float16*)alloc(featH);
  unsigned int* tmp      = (unsigned int*)alloc(padE * 4);
  int*          srcs     = (int*)alloc(padE * 4);
  float*        dinv     = (float*)alloc((size_t)n_nodes * 4);
  int*          rowbeg   = (int*)alloc((size_t)n_nodes * 4);
  int*          rowcnt   = (int*)alloc((size_t)n_nodes * 4);
  int*          gcur     = (int*)alloc((size_t)MAXBKT * 4);
  _Float16*     Wt       = (_Float16*)alloc(64 * 512 * 2);
  _Float16*     Wct      = (_Float16*)alloc(64 * 64 * 2);
  float*        bias_out = (float*)alloc(64 * 4);

  k_prep<<<5, 256, 0, stream>>>(W1, W2, b2, Wlin, blin, Wt, Wct, bias_out,
                                gcur, nbkt, cap);
  k_bin<<<ntiles, 256, 0, stream>>>(src, dst, n_edges, gcur, tmp, nbkt, cap);
  k_place<<<nbkt, 256, 0, stream>>>(tmp, gcur, rowbeg, rowcnt, dinv, srcs,
                                    n_nodes, cap);

  const int mblocks = (n_nodes + 255) / 256;
  const int agblocks = (n_nodes + 3) / 4;

  // layer 1: h1 = x @ W1 (fp16 MFMA), gather -> h1r (fp16, ReLU fused)
  k_mfma<512, false><<<mblocks, 1024, 0, stream>>>(x, Wt, feath1, n_nodes);
  k_gather<<<agblocks, 256, 0, stream>>>(feath1, rowbeg, rowcnt, srcs, dinv, b1,
                                         h1r, nullptr, n_nodes);

  // layer 2 (+ folded final linear): h2 = h1r @ (W2@Wlin), gather -> out (fp32)
  k_mfma<64, true><<<mblocks, 1024, 0, stream>>>(h1r, Wct, feath2, n_nodes);
  k_gather<<<agblocks, 256, 0, stream>>>(feath2, rowbeg, rowcnt, srcs, dinv,
                                         bias_out, nullptr, out, n_nodes);
}

// Round 11
// 570.897 us; speedup vs baseline: 5.5415x; 1.0490x over previous
//
#include <hip/hip_runtime.h>

#define DIN 512
#define DH  64
#define BKT_SHIFT 10                // 1024 nodes per bucket
#define BKT_NODES 1024
#define MAXBKT 128                  // supports up to 131072 nodes
#define TILE 8192                   // edges per binning workgroup
#define SRC_BITS 17                 // n_nodes < 131072
#define SRC_MASK ((1u << SRC_BITS) - 1)

typedef __attribute__((ext_vector_type(8))) _Float16 half8_t;
typedef __attribute__((ext_vector_type(4))) float float4_t;

// ---- fused prep + bin (grid-partitioned):
//  block 0:    Wc=W2@Wlin -> Wct fp16, bias_out=b2@Wlin+blin
//  blocks 1-4: Wt fp16 [n][k] = W1^T slice via LDS transpose
//  blocks 5+:  bin tile (blockIdx.x-5) of edges into fixed-cap bucket regions
__global__ __launch_bounds__(256) void k_prepbin(const float* __restrict__ W1,
                                                 const float* __restrict__ W2,
                                                 const float* __restrict__ b2,
                                                 const float* __restrict__ Wlin,
                                                 const float* __restrict__ blin,
                                                 _Float16* __restrict__ Wt,
                                                 _Float16* __restrict__ Wct,
                                                 float* __restrict__ bias_out,
                                                 const int* __restrict__ src,
                                                 const int* __restrict__ dst,
                                                 int n_edges,
                                                 int* __restrict__ gcur,
                                                 unsigned int* __restrict__ tmp,
                                                 int nbkt, int cap) {
  const int tid = threadIdx.x;
  if (blockIdx.x == 0) {
    __shared__ float WcS[64 * 64];
    for (int idx = tid; idx < 64 * 64; idx += 256) {
      int i = idx >> 6, j = idx & 63;
      float s = 0.f;
      #pragma unroll 8
      for (int k = 0; k < 64; ++k) s = fmaf(W2[i * 64 + k], Wlin[k * 64 + j], s);
      WcS[idx] = s;
    }
    if (tid < 64) {
      float s = blin[tid];
      #pragma unroll 8
      for (int k = 0; k < 64; ++k) s = fmaf(b2[k], Wlin[k * 64 + tid], s);
      bias_out[tid] = s;
    }
    __syncthreads();
    for (int G = tid; G < 64 * 64 / 8; G += 256) {
      int n = G >> 3, k = (G & 7) * 8;
      half8_t h;
      #pragma unroll
      for (int j = 0; j < 8; ++j) h[j] = (_Float16)WcS[(k + j) * 64 + n];
      *(half8_t*)&Wct[(size_t)n * 64 + k] = h;
    }
  } else if (blockIdx.x <= 4) {
    __shared__ _Float16 T[64][136];
    const int k0 = (blockIdx.x - 1) * 128;
    for (int idx = tid; idx < 128 * 64; idx += 256) {
      int kk = idx >> 6, n = idx & 63;
      T[n][kk] = (_Float16)W1[(size_t)(k0 + kk) * 64 + n];
    }
    __syncthreads();
    for (int G = tid; G < 64 * 16; G += 256) {
      int n = G >> 4, g = (G & 15) * 8;
      half8_t h = *(const half8_t*)&T[n][g];
      *(half8_t*)&Wt[(size_t)n * 512 + k0 + g] = h;
    }
  } else {
    __shared__ int cnt[MAXBKT];
    __shared__ int base[MAXBKT];
    for (int b = tid; b < nbkt; b += 256) cnt[b] = 0;
    __syncthreads();
    int e0 = (blockIdx.x - 5) * TILE;
    int e1 = min(e0 + TILE, n_edges);
    for (int e = e0 + tid; e < e1; e += 256)
      atomicAdd(&cnt[dst[e] >> BKT_SHIFT], 1);
    __syncthreads();
    for (int b = tid; b < nbkt; b += 256) {
      int c = cnt[b];
      base[b] = c ? (b * cap + atomicAdd(&gcur[b], c)) : 0;
      cnt[b] = 0;
    }
    __syncthreads();
    for (int e = e0 + tid; e < e1; e += 256) {
      int d = dst[e];
      int bkt = d >> BKT_SHIFT;
      int off = atomicAdd(&cnt[bkt], 1);
      int pos = base[bkt] + off;
      if (pos < (bkt + 1) * cap)  // overflow guard (never hit for random dst)
        tmp[pos] = (unsigned int)src[e] |
                   ((unsigned int)(d & (BKT_NODES - 1)) << SRC_BITS);
    }
  }
}

// ------- per-bucket: degrees -> rowbeg/rowcnt/dinv, then place srcs (4B) ------
__global__ __launch_bounds__(256) void k_place(const unsigned int* __restrict__ tmp,
                                               const int* __restrict__ gcur,
                                               int* __restrict__ rowbeg,
                                               int* __restrict__ rowcnt,
                                               float* __restrict__ dinv,
                                               int* __restrict__ srcs,
                                               int n_nodes, int cap) {
  __shared__ int cnt[BKT_NODES];
  __shared__ int sh[256];
  const int t = threadIdx.x;
  const int bkt = blockIdx.x;
  #pragma unroll
  for (int k = 0; k < BKT_NODES / 256; ++k) cnt[t + 256 * k] = 0;
  __syncthreads();
  const int beg = bkt * cap;
  const int end = beg + min(gcur[bkt], cap);
  for (int j = beg + t; j < end; j += 256)
    atomicAdd(&cnt[tmp[j] >> SRC_BITS], 1);
  __syncthreads();
  int v[4];
  int s = 0;
  const int base = t * 4;
  #pragma unroll
  for (int k = 0; k < 4; ++k) {
    v[k] = cnt[base + k];
    s += v[k];
  }
  sh[t] = s;
  __syncthreads();
  for (int off = 1; off < 256; off <<= 1) {
    int x = sh[t];
    int y = (t >= off) ? sh[t - off] : 0;
    __syncthreads();
    sh[t] = x + y;
    __syncthreads();
  }
  int excl = sh[t] - s;
  #pragma unroll
  for (int k = 0; k < 4; ++k) {
    int idx = base + k;
    int node = (bkt << BKT_SHIFT) + idx;
    if (node < n_nodes) {
      rowbeg[node] = beg + excl;
      rowcnt[node] = v[k];
      dinv[node] = rsqrtf((float)(v[k] + 1));   // +1 self loop
    }
    cnt[idx] = excl;
    excl += v[k];
  }
  __syncthreads();
  for (int j = beg + t; j < end; j += 256) {
    unsigned int e = tmp[j];
    int r = e >> SRC_BITS;
    int pos = atomicAdd(&cnt[r], 1);
    srcs[beg + pos] = (int)(e & SRC_MASK);
  }
}

// ---- MFMA fp16 GEMM + row scaling: Ch[r,:] = (fp16)( (A[r,:] @ Bt^T) * dinv[r] )
// 1024 threads = 16 waves, 256 rows/block. Bt [64][KDIM] fp16, LDS-swizzled.
// NOTE: A-operand row index = lane&15, but C/D output row = (lane>>4)*4 + reg.
// dinv must be indexed by the OUTPUT row (bug fixed in R11).
template <int KDIM, bool A_HALF>
__global__ __launch_bounds__(1024) void k_mfma(const void* __restrict__ Ain,
                                               const _Float16* __restrict__ Bt,
                                               const float* __restrict__ dinv,
                                               _Float16* __restrict__ Ch, int M) {
  constexpr int BS_HALVES = (64 * KDIM > 16384) ? 64 * KDIM : 16384;
  __shared__ _Float16 Bs[BS_HALVES];  // 64KB (K=512) / 32KB (K=64)
  const int tid = threadIdx.x;
  for (int G = tid; G < 8 * KDIM; G += 1024) {
    int n = G / (KDIM / 8);
    int g = G % (KDIM / 8);
    half8_t h = *(const half8_t*)&Bt[(size_t)G * 8];
    *(half8_t*)&Bs[n * KDIM + ((g ^ (n & 7)) * 8)] = h;
  }
  __syncthreads();

  const int wave = tid >> 6, lane = tid & 63;
  const int quad = lane >> 4, lrow = lane & 15;
  const int row = blockIdx.x * 256 + wave * 16 + lrow;
  const int rowc = min(row, M - 1);

  float4_t acc[4] = {{0.f, 0.f, 0.f, 0.f}, {0.f, 0.f, 0.f, 0.f},
                     {0.f, 0.f, 0.f, 0.f}, {0.f, 0.f, 0.f, 0.f}};

  #pragma unroll
  for (int k0 = 0; k0 < KDIM; k0 += 32) {
    half8_t a;
    if (A_HALF) {
      a = *(const half8_t*)((const _Float16*)Ain + (size_t)rowc * KDIM + k0 + quad * 8);
    } else {
      const float* Af = (const float*)Ain + (size_t)rowc * KDIM + k0 + quad * 8;
      float4 x0 = *(const float4*)Af;
      float4 x1 = *(const float4*)(Af + 4);
      a[0] = (_Float16)x0.x; a[1] = (_Float16)x0.y;
      a[2] = (_Float16)x0.z; a[3] = (_Float16)x0.w;
      a[4] = (_Float16)x1.x; a[5] = (_Float16)x1.y;
      a[6] = (_Float16)x1.z; a[7] = (_Float16)x1.w;
    }
    const int g = (k0 >> 3) + quad;
    #pragma unroll
    for (int nb = 0; nb < 4; ++nb) {
      int n = nb * 16 + lrow;
      half8_t b = *(const half8_t*)&Bs[n * KDIM + ((g ^ (n & 7)) * 8)];
      acc[nb] = __builtin_amdgcn_mfma_f32_16x16x32_f16(a, b, acc[nb], 0, 0, 0);
    }
  }

  // per-OUTPUT-row dinv (output row = wave*16 + quad*4 + r)
  const int orow_base = blockIdx.x * 256 + wave * 16 + quad * 4;
  float dnr[4];
  #pragma unroll
  for (int r = 0; r < 4; ++r) dnr[r] = dinv[min(orow_base + r, M - 1)];

  __syncthreads();
  _Float16* scratch = Bs + wave * 1024;  // 16x64 halves per wave
  #pragma unroll
  for (int nb = 0; nb < 4; ++nb)
    #pragma unroll
    for (int r = 0; r < 4; ++r)
      scratch[(quad * 4 + r) * 64 + nb * 16 + lrow] = (_Float16)(acc[nb][r] * dnr[r]);
  const int r2 = lane >> 2, c2 = (lane & 3) * 16;
  const int row_out = blockIdx.x * 256 + wave * 16 + r2;
  half8_t o0 = *(const half8_t*)&scratch[r2 * 64 + c2];
  half8_t o1 = *(const half8_t*)&scratch[r2 * 64 + c2 + 8];
  if (row_out < M) {
    *(half8_t*)&Ch[(size_t)row_out * 64 + c2] = o0;
    *(half8_t*)&Ch[(size_t)row_out * 64 + c2 + 8] = o1;
  }
}

// ---- per-node-wave CSR gather over pre-scaled rows fs = h*dinv ---------------
// lane = 8*esub + cg; out = act( dinv[n]*( sum_e fs[s_e,:] + fs[n,:] ) + bias )
__global__ __launch_bounds__(256) void k_gather(const _Float16* __restrict__ fs,
                                                const int* __restrict__ rowbeg,
                                                const int* __restrict__ rowcnt,
                                                const int* __restrict__ srcs,
                                                const float* __restrict__ dinv,
                                                const float* __restrict__ bias,
                                                _Float16* __restrict__ outh,
                                                float* __restrict__ outf,
                                                int n_nodes) {
  int node = blockIdx.x * 4 + (threadIdx.x >> 6);
  int lane = threadIdx.x & 63;
  if (node >= n_nodes) return;
  const int esub = lane >> 3;       // 0..7 edge slot
  const int ch8 = (lane & 7) * 8;   // channel group base
  const int beg = rowbeg[node];
  const int end = beg + rowcnt[node];
  float acc[8] = {0.f, 0.f, 0.f, 0.f, 0.f, 0.f, 0.f, 0.f};
  int j = beg;
  for (; j + 16 <= end; j += 16) {
    int s0 = srcs[j + esub];
    int s1 = srcs[j + 8 + esub];
    half8_t f0 = *(const half8_t*)&fs[(size_t)s0 * 64 + ch8];
    half8_t f1 = *(const half8_t*)&fs[(size_t)s1 * 64 + ch8];
    #pragma unroll
    for (int k = 0; k < 8; ++k) acc[k] += (float)f0[k];
    #pragma unroll
    for (int k = 0; k < 8; ++k) acc[k] += (float)f1[k];
  }
  for (; j < end; j += 8) {
    int idx = j + esub;
    bool act = idx < end;
    int s = srcs[act ? idx : beg];
    float w = act ? 1.f : 0.f;
    half8_t f = *(const half8_t*)&fs[(size_t)s * 64 + ch8];
    #pragma unroll
    for (int k = 0; k < 8; ++k) acc[k] = fmaf((float)f[k], w, acc[k]);
  }
  // reduce across the 8 edge slots (lane bits 3,4,5)
  #pragma unroll
  for (int m = 8; m <= 32; m <<= 1)
    #pragma unroll
    for (int k = 0; k < 8; ++k) acc[k] += __shfl_xor(acc[k], m, 64);
  if (esub == 0) {
    float dn = dinv[node];
    half8_t sf = *(const half8_t*)&fs[(size_t)node * 64 + ch8];
    float v[8];
    #pragma unroll
    for (int k = 0; k < 8; ++k)
      v[k] = fmaf(acc[k] + (float)sf[k], dn, bias[ch8 + k]);
    if (outh) {
      half8_t o;
      #pragma unroll
      for (int k = 0; k < 8; ++k) o[k] = (_Float16)fmaxf(v[k], 0.f);
      *(half8_t*)&outh[(size_t)node * 64 + ch8] = o;
    } else {
      float4 o0 = make_float4(v[0], v[1], v[2], v[3]);
      float4 o1 = make_float4(v[4], v[5], v[6], v[7]);
      *(float4*)&outf[(size_t)node * 64 + ch8] = o0;
      *(float4*)&outf[(size_t)node * 64 + ch8 + 4] = o1;
    }
  }
}

extern "C" void kernel_launch(void* const* d_in, const int* in_sizes, int n_in,
                              void* d_out, int out_size, void* d_ws, size_t ws_size,
                              hipStream_t stream) {
  const float* x    = (const float*)d_in[0];
  const int*   ei   = (const int*)d_in[1];
  const float* W1   = (const float*)d_in[2];
  const float* b1   = (const float*)d_in[3];
  const float* W2   = (const float*)d_in[4];
  const float* b2   = (const float*)d_in[5];
  const float* Wlin = (const float*)d_in[6];
  const float* blin = (const float*)d_in[7];
  float* out = (float*)d_out;

  const int n_nodes = in_sizes[0] / DIN;
  const int n_edges = in_sizes[1] / 2;
  const int* src = ei;
  const int* dst = ei + n_edges;
  const int nbkt = (n_nodes + BKT_NODES - 1) >> BKT_SHIFT;
  const int ntiles = (n_edges + TILE - 1) / TILE;
  const int cap = ((n_edges / nbkt) * 5 / 4 + 1024 + 255) & ~255;  // bucket capacity

  char* ws = (char*)d_ws;
  size_t off = 0;
  auto alloc = [&](size_t bytes) {
    void* p = ws + off;
    off += (bytes + 255) & ~(size_t)255;
    return p;
  };
  const size_t featH = (size_t)n_nodes * DH * 2;
  const size_t padE = (size_t)nbkt * cap;
  _Float16*     fs1      = (_Float16*)alloc(featH);   // (x@W1)*dinv fp16
  _Float16*     h1r      = (_Float16*)alloc(featH);   // relu'd layer-1 out, fp16
  _Float16*     fs2      = (_Float16*)alloc(featH);   // (h1r@Wc)*dinv fp16
  unsigned int* tmp      = (unsigned int*)alloc(padE * 4);
  int*          srcs     = (int*)alloc(padE * 4);
  float*        dinv     = (float*)alloc((size_t)n_nodes * 4);
  int*          rowbeg   = (int*)alloc((size_t)n_nodes * 4);
  int*          rowcnt   = (int*)alloc((size_t)n_nodes * 4);
  int*          gcur     = (int*)alloc((size_t)MAXBKT * 4);
  _Float16*     Wt       = (_Float16*)alloc(64 * 512 * 2);
  _Float16*     Wct      = (_Float16*)alloc(64 * 64 * 2);
  float*        bias_out = (float*)alloc(64 * 4);

  hipMemsetAsync(gcur, 0, (size_t)nbkt * 4, stream);

  k_prepbin<<<5 + ntiles, 256, 0, stream>>>(W1, W2, b2, Wlin, blin, Wt, Wct,
                                            bias_out, src, dst, n_edges, gcur,
                                            tmp, nbkt, cap);
  k_place<<<nbkt, 256, 0, stream>>>(tmp, gcur, rowbeg, rowcnt, dinv, srcs,
                                    n_nodes, cap);

  const int mblocks = (n_nodes + 255) / 256;
  const int agblocks = (n_nodes + 3) / 4;

  // layer 1: fs1 = (x@W1)*dinv (fp16 MFMA), gather -> h1r (fp16, ReLU fused)
  k_mfma<512, false><<<mblocks, 1024, 0, stream>>>(x, Wt, dinv, fs1, n_nodes);
  k_gather<<<agblocks, 256, 0, stream>>>(fs1, rowbeg, rowcnt, srcs, dinv, b1,
                                         h1r, nullptr, n_nodes);

  // layer 2 (+ folded final linear): fs2 = (h1r@Wc)*dinv, gather -> out (fp32)
  k_mfma<64, true><<<mblocks, 1024, 0, stream>>>(h1r, Wct, dinv, fs2, n_nodes);
  k_gather<<<agblocks, 256, 0, stream>>>(fs2, rowbeg, rowcnt, srcs, dinv,
                                         bias_out, nullptr, out, n_nodes);
}